// Round 7
// baseline (2145.664 us; speedup 1.0000x reference)
//
#include <hip/hip_runtime.h>

// Problem constants
#define NB   1024
#define NN   65536
#define NF   64
#define ND   512
#define NDB  1024
#define NC   96

// scores/topk chunk of B rows; values-path chunk
#define BB_C 256
#define BB_D 128

// top-k segmentation
#define TK_SPLIT 16
#define TK_SEG   (NN / TK_SPLIT)   // 4096
#define TK_CAND  (TK_SPLIT * NC)   // 1536

typedef unsigned short ushort;
typedef __attribute__((ext_vector_type(8))) short short8;
typedef __attribute__((ext_vector_type(4))) float floatx4;

__device__ __forceinline__ ushort f2bf(float f) {   // RNE f32->bf16
    unsigned u = __float_as_uint(f);
    u += 0x7fffu + ((u >> 16) & 1u);
    return (ushort)(u >> 16);
}
__device__ __forceinline__ float bf2f(ushort h) {
    return __uint_as_float(((unsigned)h) << 16);
}
// LDS plane: [m][k] bf16, k-stride 32, 16B-chunk XOR swizzle -> conflict-free
__device__ __forceinline__ int lds_off(int m, int c) {
    return m * 32 + (((c + (m >> 1)) & 3) << 3);
}

// async global->LDS 16B
__device__ __forceinline__ void gload16(const ushort* g, ushort* l)
{
    void* gv = (void*)g;
    void* lv = (void*)l;
    __builtin_amdgcn_global_load_lds(
        (__attribute__((address_space(1))) void*)gv,
        (__attribute__((address_space(3))) void*)lv, 16, 0, 0);
}

// XCD contiguous-slab swizzle (T1 variant): XCD i (= wg%8 launch order)
// processes the contiguous x-fastest tile range [i*nwg/8, (i+1)*nwg/8).
// Sibling col-tiles of one A row-panel become temporally-adjacent blocks on
// ONE XCD -> panel fetched ~once per L2 instead of 8x across XCDs.
// r4->r5: e2 FETCH 229->~110 MB class fix, wall -312 us. Bijective when
// nwg%8==0 (all remapped grids here); identity otherwise.
__device__ __forceinline__ void xcd_slab(int& bx, int& by)
{
    const int gx  = gridDim.x;
    const int nwg = gx * gridDim.y;
    int x = blockIdx.x, y = blockIdx.y;
    if (!(nwg & 7)) {
        const int wg = y * gx + x;
        const int t  = (wg & 7) * (nwg >> 3) + (wg >> 3);
        x = t % gx; y = t / gx;
    }
    bx = x; by = y;
}

// ---------------------------------------------------------------------------
// Split-plane MFMA GEMM (f32-emulating, 3 MFMA), NT, 128x128 tile.
// SCORES kernel. 1024-block grid -> 4 blocks/CU: cross-block overlap hides
// the per-iteration barrier drain (768-780 TF measured r5/r6 = structure
// ceiling; FETCH = 1x CK read). NOT slab-swizzled (r11 measurement; swizzle
// costs ~2% in L3-fit regimes).
// ---------------------------------------------------------------------------
__global__ __launch_bounds__(256) void gemm_ss(
    const ushort* __restrict__ Ah_g, const ushort* __restrict__ Al_g,
    const ushort* __restrict__ Bh_g, const ushort* __restrict__ Bl_g,
    const float* __restrict__ scoresq, float* __restrict__ Sf,
    int M, int N, int K)
{
    __shared__ ushort Ah[128 * 32], Al[128 * 32];
    __shared__ ushort Bh[128 * 32], Bl[128 * 32];
    const int tid = threadIdx.x;
    const int lane = tid & 63, wid = tid >> 6;
    const int wm = (wid & 1) * 64, wn = (wid >> 1) * 64;
    const int lane15 = lane & 15, quad = lane >> 4;
    const int row0 = blockIdx.y * 128, col0 = blockIdx.x * 128;

    const int srow = tid >> 2;
    const int scl  = tid & 3;
    const int cp   = (scl - (srow >> 1)) & 3;
    const size_t ga0 = (size_t)(row0 + srow) * K + cp * 8;
    const size_t ga1 = (size_t)(row0 + 64 + srow) * K + cp * 8;
    const size_t gb0 = (size_t)(col0 + srow) * K + cp * 8;
    const size_t gb1 = (size_t)(col0 + 64 + srow) * K + cp * 8;
    const int l0 = tid * 8;
    const int l1 = 2048 + tid * 8;

    floatx4 acc[4][4];
#pragma unroll
    for (int i = 0; i < 4; i++)
#pragma unroll
        for (int j = 0; j < 4; j++) acc[i][j] = (floatx4){0.f, 0.f, 0.f, 0.f};

    for (int k0 = 0; k0 < K; k0 += 32) {
        __syncthreads();
        gload16(Ah_g + ga0 + k0, Ah + l0);
        gload16(Ah_g + ga1 + k0, Ah + l1);
        gload16(Al_g + ga0 + k0, Al + l0);
        gload16(Al_g + ga1 + k0, Al + l1);
        gload16(Bh_g + gb0 + k0, Bh + l0);
        gload16(Bh_g + gb1 + k0, Bh + l1);
        gload16(Bl_g + gb0 + k0, Bl + l0);
        gload16(Bl_g + gb1 + k0, Bl + l1);
        __syncthreads();

        short8 ah[4], al[4], bh[4], bl[4];
#pragma unroll
        for (int t = 0; t < 4; t++) {
            const int am = wm + t * 16 + lane15;
            const int bn = wn + t * 16 + lane15;
            ah[t] = *(const short8*)(Ah + lds_off(am, quad));
            al[t] = *(const short8*)(Al + lds_off(am, quad));
            bh[t] = *(const short8*)(Bh + lds_off(bn, quad));
            bl[t] = *(const short8*)(Bl + lds_off(bn, quad));
        }
#pragma unroll
        for (int i = 0; i < 4; i++)
#pragma unroll
            for (int j = 0; j < 4; j++) {
                acc[i][j] = __builtin_amdgcn_mfma_f32_16x16x32_bf16(ah[i], bh[j], acc[i][j], 0, 0, 0);
                acc[i][j] = __builtin_amdgcn_mfma_f32_16x16x32_bf16(ah[i], bl[j], acc[i][j], 0, 0, 0);
                acc[i][j] = __builtin_amdgcn_mfma_f32_16x16x32_bf16(al[i], bh[j], acc[i][j], 0, 0, 0);
            }
    }

    // C/D layout: col=lane&15, row=quad*4+reg  [m89]
#pragma unroll
    for (int i = 0; i < 4; i++)
#pragma unroll
        for (int j = 0; j < 4; j++) {
            const int gc = col0 + wn + j * 16 + lane15;
            const int rb = row0 + wm + i * 16 + quad * 4;
            const float sv = scoresq[gc];
#pragma unroll
            for (int r = 0; r < 4; r++) {
                const size_t o = (size_t)(rb + r) * N + gc;
                Sf[o] = sv - 2.f * acc[i][j][r];
            }
        }
}

// ---------------------------------------------------------------------------
// Split-plane GEMM, 128M x 64N tile, BK=64. Full 3-MFMA (B-lo required:
// dropping it measured absmax 0.047 -- do not re-try). Now used for e1, e2,
// kw, lin: 24 MFMA per kk = 2x the 64^2 tile's per-barrier MFMA density,
// same A-refetch, grids 832-1664 blocks (3.25-6.5/CU).
// Slab-swizzled: sibling col-tiles of each A panel -> one XCD.
// NOTE: resh/resl/Ch/Cl NOT __restrict__ -- e2 runs in-place (Ch==resh,
// same-thread read-before-write per element; proven pattern since r3).
// ---------------------------------------------------------------------------
__global__ __launch_bounds__(256) void gemm_ss_n64(
    const ushort* __restrict__ Ah_g, const ushort* __restrict__ Al_g,
    const ushort* __restrict__ Bh_g, const ushort* __restrict__ Bl_g,
    const float* __restrict__ bias,
    const ushort* resh, const ushort* resl,
    ushort* Ch, ushort* Cl,
    int M, int N, int K, int relu)
{
    __shared__ ushort Ah[128 * 64], Al[128 * 64];
    __shared__ ushort Bh[64 * 64], Bl[64 * 64];
    const int tid = threadIdx.x;
    const int lane = tid & 63, wid = tid >> 6;
    const int wm = wid * 32;
    const int lane15 = lane & 15, quad = lane >> 4;
    int bx, by; xcd_slab(bx, by);
    const int row0 = by * 128, col0 = bx * 64;

    const int srow = tid >> 2;
    const int scl  = tid & 3;
    const int cp   = (scl - (srow >> 1)) & 3;
    const size_t ga0 = (size_t)(row0 + srow) * K + cp * 8;
    const size_t ga1 = (size_t)(row0 + 64 + srow) * K + cp * 8;
    const size_t gb  = (size_t)(col0 + srow) * K + cp * 8;
    const int l0 = tid * 8;
    const int l1 = 2048 + tid * 8;

    floatx4 acc[2][4];
#pragma unroll
    for (int i = 0; i < 2; i++)
#pragma unroll
        for (int j = 0; j < 4; j++) acc[i][j] = (floatx4){0.f, 0.f, 0.f, 0.f};

    for (int k0 = 0; k0 < K; k0 += 64) {
        __syncthreads();
        gload16(Ah_g + ga0 + k0,      Ah + l0);
        gload16(Ah_g + ga1 + k0,      Ah + l1);
        gload16(Ah_g + ga0 + k0 + 32, Ah + 4096 + l0);
        gload16(Ah_g + ga1 + k0 + 32, Ah + 4096 + l1);
        gload16(Al_g + ga0 + k0,      Al + l0);
        gload16(Al_g + ga1 + k0,      Al + l1);
        gload16(Al_g + ga0 + k0 + 32, Al + 4096 + l0);
        gload16(Al_g + ga1 + k0 + 32, Al + 4096 + l1);
        gload16(Bh_g + gb + k0,       Bh + l0);
        gload16(Bh_g + gb + k0 + 32,  Bh + 2048 + l0);
        gload16(Bl_g + gb + k0,       Bl + l0);
        gload16(Bl_g + gb + k0 + 32,  Bl + 2048 + l0);
        __syncthreads();

#pragma unroll
        for (int kk = 0; kk < 2; kk++) {
            const int ao = kk * 4096, bo = kk * 2048;
            short8 ah[2], al[2], bh[4], bl[4];
#pragma unroll
            for (int t = 0; t < 2; t++) {
                const int am = wm + t * 16 + lane15;
                ah[t] = *(const short8*)(Ah + ao + lds_off(am, quad));
                al[t] = *(const short8*)(Al + ao + lds_off(am, quad));
            }
#pragma unroll
            for (int j = 0; j < 4; j++) {
                const int bn = j * 16 + lane15;
                bh[j] = *(const short8*)(Bh + bo + lds_off(bn, quad));
                bl[j] = *(const short8*)(Bl + bo + lds_off(bn, quad));
            }
#pragma unroll
            for (int i = 0; i < 2; i++)
#pragma unroll
                for (int j = 0; j < 4; j++) {
                    acc[i][j] = __builtin_amdgcn_mfma_f32_16x16x32_bf16(ah[i], bh[j], acc[i][j], 0, 0, 0);
                    acc[i][j] = __builtin_amdgcn_mfma_f32_16x16x32_bf16(ah[i], bl[j], acc[i][j], 0, 0, 0);
                    acc[i][j] = __builtin_amdgcn_mfma_f32_16x16x32_bf16(al[i], bh[j], acc[i][j], 0, 0, 0);
                }
        }
    }

#pragma unroll
    for (int i = 0; i < 2; i++)
#pragma unroll
        for (int j = 0; j < 4; j++) {
            const int gc = col0 + j * 16 + lane15;
            const int rb = row0 + wm + i * 16 + quad * 4;
            const float bv = bias ? bias[gc] : 0.f;
#pragma unroll
            for (int r = 0; r < 4; r++) {
                const size_t o = (size_t)(rb + r) * N + gc;
                float v = acc[i][j][r] + bv;
                if (resh) v += bf2f(resh[o]) + bf2f(resl[o]);
                if (relu) v = fmaxf(v, 0.f);
                ushort h = f2bf(v);
                Ch[o] = h;
                Cl[o] = f2bf(v - bf2f(h));
            }
        }
}

// ---------------------------------------------------------------------------
// Small-M split-plane GEMM: 64x64 tile, BK=64, full 3-MFMA. Flexible epi.
// NOTE: resh/resl/Ch/Cl are NOT __restrict__ (in-place support).
// Slab-swizzled. Now used only for the predictor block (M=1024, small).
// ---------------------------------------------------------------------------
__global__ __launch_bounds__(256) void gemm_ss_small(
    const ushort* __restrict__ Ah_g, const ushort* __restrict__ Al_g,
    const ushort* __restrict__ Bh_g, const ushort* __restrict__ Bl_g,
    const float* __restrict__ bias,
    const ushort* resh, const ushort* resl,
    const float* resf,
    ushort* Ch, ushort* Cl,
    float* outf,
    int M, int N, int K, int relu)
{
    __shared__ ushort Ah[64 * 64], Al[64 * 64];
    __shared__ ushort Bh[64 * 64], Bl[64 * 64];
    const int tid = threadIdx.x;
    const int lane = tid & 63, wid = tid >> 6;
    const int wm = (wid & 1) * 32, wn = (wid >> 1) * 32;
    const int lane15 = lane & 15, quad = lane >> 4;
    int bx, by; xcd_slab(bx, by);
    const int row0 = by * 64, col0 = bx * 64;

    const int srow = tid >> 2;          // 0..63
    const int scl  = tid & 3;
    const int cp   = (scl - (srow >> 1)) & 3;
    const size_t ga = (size_t)(row0 + srow) * K + cp * 8;
    const size_t gb = (size_t)(col0 + srow) * K + cp * 8;
    const int l = tid * 8;

    floatx4 acc[2][2];
#pragma unroll
    for (int i = 0; i < 2; i++)
#pragma unroll
        for (int j = 0; j < 2; j++) acc[i][j] = (floatx4){0.f, 0.f, 0.f, 0.f};

    for (int k0 = 0; k0 < K; k0 += 64) {
        __syncthreads();
        gload16(Ah_g + ga + k0,      Ah + l);
        gload16(Ah_g + ga + k0 + 32, Ah + 2048 + l);
        gload16(Al_g + ga + k0,      Al + l);
        gload16(Al_g + ga + k0 + 32, Al + 2048 + l);
        gload16(Bh_g + gb + k0,      Bh + l);
        gload16(Bh_g + gb + k0 + 32, Bh + 2048 + l);
        gload16(Bl_g + gb + k0,      Bl + l);
        gload16(Bl_g + gb + k0 + 32, Bl + 2048 + l);
        __syncthreads();

#pragma unroll
        for (int kk = 0; kk < 2; kk++) {
            const int so = kk * 2048;
            short8 ah[2], al[2], bh[2], bl[2];
#pragma unroll
            for (int t = 0; t < 2; t++) {
                const int am = wm + t * 16 + lane15;
                const int bn = wn + t * 16 + lane15;
                ah[t] = *(const short8*)(Ah + so + lds_off(am, quad));
                al[t] = *(const short8*)(Al + so + lds_off(am, quad));
                bh[t] = *(const short8*)(Bh + so + lds_off(bn, quad));
                bl[t] = *(const short8*)(Bl + so + lds_off(bn, quad));
            }
#pragma unroll
            for (int i = 0; i < 2; i++)
#pragma unroll
                for (int j = 0; j < 2; j++) {
                    acc[i][j] = __builtin_amdgcn_mfma_f32_16x16x32_bf16(ah[i], bh[j], acc[i][j], 0, 0, 0);
                    acc[i][j] = __builtin_amdgcn_mfma_f32_16x16x32_bf16(ah[i], bl[j], acc[i][j], 0, 0, 0);
                    acc[i][j] = __builtin_amdgcn_mfma_f32_16x16x32_bf16(al[i], bh[j], acc[i][j], 0, 0, 0);
                }
        }
    }

#pragma unroll
    for (int i = 0; i < 2; i++)
#pragma unroll
        for (int j = 0; j < 2; j++) {
            const int gc = col0 + wn + j * 16 + lane15;
            const int rb = row0 + wm + i * 16 + quad * 4;
            const float bv = bias ? bias[gc] : 0.f;
#pragma unroll
            for (int r = 0; r < 4; r++) {
                const size_t o = (size_t)(rb + r) * N + gc;
                float v = acc[i][j][r] + bv;
                if (resh) v += bf2f(resh[o]) + bf2f(resl[o]);
                if (resf) v += resf[o];
                if (relu) v = fmaxf(v, 0.f);
                if (outf) outf[o] = v;
                if (Ch) {
                    ushort h = f2bf(v);
                    Ch[o] = h;
                    Cl[o] = f2bf(v - bf2f(h));
                }
            }
        }
}

// ---------------------------------------------------------------------------
// Values diff precompute: DD[r][:] = bf16((kx[b_loc] planes) - (ck[idx] planes))
// ---------------------------------------------------------------------------
__global__ __launch_bounds__(256) void diff_pl_kernel(
    const ushort* __restrict__ kxh, const ushort* __restrict__ kxl,  // +b0*ND
    const ushort* __restrict__ ckh, const ushort* __restrict__ ckl,
    const int* __restrict__ idx,                                     // +b0*NC
    ushort* __restrict__ DD, int Mrows)
{
    const int g = blockIdx.x * 256 + threadIdx.x;   // 8-elem group id
    if (g >= Mrows * (ND / 8)) return;
    const int r  = g >> 6;               // ND/8 = 64 groups per row
    const int d  = (g & 63) * 8;
    const int b_loc = r / NC;
    const int ci = idx[r];
    const size_t xb = (size_t)b_loc * ND + d;
    const size_t cb = (size_t)ci * ND + d;

    short8 xh = *(const short8*)(kxh + xb);
    short8 xl = *(const short8*)(kxl + xb);
    short8 ch = *(const short8*)(ckh + cb);
    short8 cl = *(const short8*)(ckl + cb);
    short8 dd;
#pragma unroll
    for (int i = 0; i < 8; i++) {
        const float a = bf2f((ushort)xh[i]) + bf2f((ushort)xl[i]);
        const float c = bf2f((ushort)ch[i]) + bf2f((ushort)cl[i]);
        dd[i] = (short)f2bf(a - c);
    }
    *(short8*)(DD + (size_t)r * ND + d) = dd;
}

// ---------------------------------------------------------------------------
// Plain bf16 GEMM: A [M][K], B hi plane [N][K]: C = A @ B^T (+bias, relu)
// 128M x 64N tile, BK=64. Output bf16 (Cbf) and/or f32 (Cf). Slab-swizzled.
// Used for values T1 (DD @ t1^T -> TT) and T2 (TT @ t2^T -> VAL).
// ---------------------------------------------------------------------------
__global__ __launch_bounds__(256) void gemm_bf16_n64(
    const ushort* __restrict__ A, const ushort* __restrict__ BTh,
    const float* __restrict__ bias,
    ushort* __restrict__ Cbf, float* __restrict__ Cf,
    int M, int N, int K, int relu)
{
    __shared__ ushort Ah[128 * 64];
    __shared__ ushort Bh[64 * 64];
    const int tid = threadIdx.x;
    const int lane = tid & 63, wid = tid >> 6;
    const int wm = wid * 32;
    const int lane15 = lane & 15, quad = lane >> 4;
    int bx, by; xcd_slab(bx, by);
    const int row0 = by * 128, col0 = bx * 64;

    const int srow = tid >> 2;
    const int scl  = tid & 3;
    const int cp   = (scl - (srow >> 1)) & 3;
    const size_t ga0 = (size_t)(row0 + srow) * K + cp * 8;
    const size_t ga1 = (size_t)(row0 + 64 + srow) * K + cp * 8;
    const size_t gb  = (size_t)(col0 + srow) * K + cp * 8;
    const int l0 = tid * 8, l1 = 2048 + tid * 8;

    floatx4 acc[2][4];
#pragma unroll
    for (int i = 0; i < 2; i++)
#pragma unroll
        for (int j = 0; j < 4; j++) acc[i][j] = (floatx4){0.f, 0.f, 0.f, 0.f};

    for (int k0 = 0; k0 < K; k0 += 64) {
        __syncthreads();
        gload16(A + ga0 + k0,      Ah + l0);
        gload16(A + ga1 + k0,      Ah + l1);
        gload16(A + ga0 + k0 + 32, Ah + 4096 + l0);
        gload16(A + ga1 + k0 + 32, Ah + 4096 + l1);
        gload16(BTh + gb + k0,      Bh + l0);
        gload16(BTh + gb + k0 + 32, Bh + 2048 + l0);
        __syncthreads();

#pragma unroll
        for (int kk = 0; kk < 2; kk++) {
            const int ao = kk * 4096, bo = kk * 2048;
            short8 ah[2], bh[4];
#pragma unroll
            for (int t = 0; t < 2; t++)
                ah[t] = *(const short8*)(Ah + ao + lds_off(wm + t * 16 + lane15, quad));
#pragma unroll
            for (int j = 0; j < 4; j++)
                bh[j] = *(const short8*)(Bh + bo + lds_off(j * 16 + lane15, quad));
#pragma unroll
            for (int i = 0; i < 2; i++)
#pragma unroll
                for (int j = 0; j < 4; j++)
                    acc[i][j] = __builtin_amdgcn_mfma_f32_16x16x32_bf16(ah[i], bh[j], acc[i][j], 0, 0, 0);
        }
    }

#pragma unroll
    for (int i = 0; i < 2; i++)
#pragma unroll
        for (int j = 0; j < 4; j++) {
            const int gc = col0 + j * 16 + lane15;
            const int rb = row0 + wm + i * 16 + quad * 4;
            const float bv = bias ? bias[gc] : 0.f;
#pragma unroll
            for (int rr = 0; rr < 4; rr++) {
                const size_t o = (size_t)(rb + rr) * N + gc;
                float v = acc[i][j][rr] + bv;
                if (relu) v = fmaxf(v, 0.f);
                if (Cbf) Cbf[o] = f2bf(v);
                if (Cf)  Cf[o] = v;
            }
        }
}

// ---------------------------------------------------------------------------
// Prep kernels
// ---------------------------------------------------------------------------
__global__ __launch_bounds__(256) void split_wt_kernel(
    const float* __restrict__ W, ushort* __restrict__ WTh,
    ushort* __restrict__ WTl, int K, int N)
{
    const int o = blockIdx.x * 256 + threadIdx.x;
    if (o < K * N) {
        const int n = o / K, k = o - n * K;
        const float x = W[(size_t)k * N + n];
        const ushort h = f2bf(x);
        WTh[o] = h;
        WTl[o] = f2bf(x - bf2f(h));
    }
}

__global__ __launch_bounds__(256) void split_pl_kernel(
    const float* __restrict__ X, ushort* __restrict__ Xh,
    ushort* __restrict__ Xl, int n)
{
    const int i = blockIdx.x * 256 + threadIdx.x;
    if (i < n) {
        const float x = X[i];
        const ushort h = f2bf(x);
        Xh[i] = h;
        Xl[i] = f2bf(x - bf2f(h));
    }
}

// ---------------------------------------------------------------------------
// LayerNorm rows of 512, f32 in / f32 out
// ---------------------------------------------------------------------------
__global__ __launch_bounds__(256) void ln_kernel(
    const float* __restrict__ X, const float* __restrict__ g,
    const float* __restrict__ b, float* __restrict__ Y, int relu)
{
    const int lane = threadIdx.x & 63;
    const int row  = blockIdx.x * 4 + (threadIdx.x >> 6);
    const float* x = X + (size_t)row * ND;
    const int d = lane * 8;

    float4 v0 = *(const float4*)(x + d);
    float4 v1 = *(const float4*)(x + d + 4);
    float s = v0.x + v0.y + v0.z + v0.w + v1.x + v1.y + v1.z + v1.w;
    float q = v0.x*v0.x + v0.y*v0.y + v0.z*v0.z + v0.w*v0.w
            + v1.x*v1.x + v1.y*v1.y + v1.z*v1.z + v1.w*v1.w;
#pragma unroll
    for (int off = 32; off; off >>= 1) {
        s += __shfl_down(s, off);
        q += __shfl_down(q, off);
    }
    s = __shfl(s, 0); q = __shfl(q, 0);
    const float mean = s * (1.f / ND);
    const float var  = q * (1.f / ND) - mean * mean;
    const float rs   = rsqrtf(var + 1e-5f);

    float4 g0 = *(const float4*)(g + d);
    float4 g1 = *(const float4*)(g + d + 4);
    float4 b0 = *(const float4*)(b + d);
    float4 b1 = *(const float4*)(b + d + 4);
    float4 o0, o1;
    o0.x = (v0.x - mean) * rs * g0.x + b0.x;
    o0.y = (v0.y - mean) * rs * g0.y + b0.y;
    o0.z = (v0.z - mean) * rs * g0.z + b0.z;
    o0.w = (v0.w - mean) * rs * g0.w + b0.w;
    o1.x = (v1.x - mean) * rs * g1.x + b1.x;
    o1.y = (v1.y - mean) * rs * g1.y + b1.y;
    o1.z = (v1.z - mean) * rs * g1.z + b1.z;
    o1.w = (v1.w - mean) * rs * g1.w + b1.w;
    if (relu) {
        o0.x = fmaxf(o0.x, 0.f); o0.y = fmaxf(o0.y, 0.f);
        o0.z = fmaxf(o0.z, 0.f); o0.w = fmaxf(o0.w, 0.f);
        o1.x = fmaxf(o1.x, 0.f); o1.y = fmaxf(o1.y, 0.f);
        o1.z = fmaxf(o1.z, 0.f); o1.w = fmaxf(o1.w, 0.f);
    }
    float* y = Y + (size_t)row * ND;
    *(float4*)(y + d)     = o0;
    *(float4*)(y + d + 4) = o1;
}

// LayerNorm rows of 512, planes in / planes out
__global__ __launch_bounds__(256) void ln_pl_kernel(
    const ushort* __restrict__ Xh, const ushort* __restrict__ Xl,
    const float* __restrict__ g, const float* __restrict__ b,
    ushort* __restrict__ Yh, ushort* __restrict__ Yl)
{
    const int lane = threadIdx.x & 63;
    const int row  = blockIdx.x * 4 + (threadIdx.x >> 6);
    const int d = lane * 8;
    const size_t base = (size_t)row * ND + d;

    short8 xh = *(const short8*)(Xh + base);
    short8 xl = *(const short8*)(Xl + base);
    float v[8];
#pragma unroll
    for (int i = 0; i < 8; i++) v[i] = bf2f((ushort)xh[i]) + bf2f((ushort)xl[i]);

    float s = 0.f, q = 0.f;
#pragma unroll
    for (int i = 0; i < 8; i++) { s += v[i]; q += v[i] * v[i]; }
#pragma unroll
    for (int off = 32; off; off >>= 1) {
        s += __shfl_down(s, off);
        q += __shfl_down(q, off);
    }
    s = __shfl(s, 0); q = __shfl(q, 0);
    const float mean = s * (1.f / ND);
    const float var  = q * (1.f / ND) - mean * mean;
    const float rs   = rsqrtf(var + 1e-5f);

    short8 yh, yl;
#pragma unroll
    for (int i = 0; i < 8; i++) {
        const float o = (v[i] - mean) * rs * g[d + i] + b[d + i];
        const ushort h = f2bf(o);
        yh[i] = (short)h;
        yl[i] = (short)f2bf(o - bf2f(h));
    }
    *(short8*)(Yh + base) = yh;
    *(short8*)(Yl + base) = yl;
}

__global__ __launch_bounds__(256) void sqnorm_pl_kernel(
    const ushort* __restrict__ Xh, const ushort* __restrict__ Xl,
    float* __restrict__ sq)
{
    const int lane = threadIdx.x & 63;
    const int row  = blockIdx.x * 4 + (threadIdx.x >> 6);
    const size_t base = (size_t)row * ND + lane * 8;
    short8 xh = *(const short8*)(Xh + base);
    short8 xl = *(const short8*)(Xl + base);
    float q = 0.f;
#pragma unroll
    for (int i = 0; i < 8; i++) {
        float v = bf2f((ushort)xh[i]) + bf2f((ushort)xl[i]);
        q += v * v;
    }
#pragma unroll
    for (int off = 32; off; off >>= 1) q += __shfl_down(q, off);
    if (lane == 0) sq[row] = q;
}

// ---------------------------------------------------------------------------
// Two-stage exact top-96: adaptive-range radix select.
// ---------------------------------------------------------------------------
__device__ __forceinline__ unsigned fkey(float f)
{
    unsigned u = __float_as_uint(f);
    return (u & 0x80000000u) ? ~u : (u | 0x80000000u);
}
__device__ __forceinline__ float inv_fkey(unsigned u)
{
    return __uint_as_float((u & 0x80000000u) ? (u & 0x7FFFFFFFu) : ~u);
}

struct SelState {
    unsigned lo;
    unsigned long long hi;   // exclusive
    int krem;
    int done;
    unsigned long long T;    // threshold
    int need;                // how many keys == T to take
};

template <int KPT>
__device__ __forceinline__ void adaptive_select(
    const unsigned (&key)[KPT], unsigned* hist, unsigned* wtot,
    SelState* st, int tid, int kwant)
{
    const int lane = tid & 63, wid = tid >> 6;

    unsigned mn = 0xFFFFFFFFu, mx = 0u;
#pragma unroll
    for (int j = 0; j < KPT; j++) {
        mn = min(mn, key[j]);
        mx = max(mx, key[j]);
    }
#pragma unroll
    for (int off = 32; off; off >>= 1) {
        mn = min(mn, (unsigned)__shfl_down((int)mn, off));
        mx = max(mx, (unsigned)__shfl_down((int)mx, off));
    }
    if (lane == 0) { hist[wid] = mn; hist[8 + wid] = mx; }
    if (tid == 0) st->done = 0;
    __syncthreads();
    if (tid == 0) {
        unsigned gmn = min(min(hist[0], hist[1]), min(hist[2], hist[3]));
        unsigned gmx = max(max(hist[8], hist[9]), max(hist[10], hist[11]));
        st->lo = gmn;
        st->hi = (unsigned long long)gmx + 1ull;
        st->krem = kwant;
    }
    __syncthreads();

    for (int iter = 0; iter < 6 && !st->done; iter++) {
        const unsigned lo = st->lo;
        const unsigned long long hi = st->hi;
        const int krem = st->krem;
        const unsigned long long span = hi - lo;
        int shift = 0;
        if (span > 256ull) {
            const int nb = 64 - __builtin_clzll(span - 1ull);
            shift = nb - 8;
        }
        hist[tid] = 0u;
        __syncthreads();
#pragma unroll
        for (int j = 0; j < KPT; j++) {
            const unsigned u = key[j];
            if (u >= lo && (unsigned long long)u < hi)
                atomicAdd(&hist[(u - lo) >> shift], 1u);
        }
        __syncthreads();
        const unsigned c = hist[tid];
        unsigned v = c;
#pragma unroll
        for (int off = 1; off < 64; off <<= 1) {
            const unsigned t = (unsigned)__shfl_up((int)v, off);
            if (lane >= off) v += t;
        }
        if (lane == 63) wtot[wid] = v;
        __syncthreads();
        unsigned pre = 0;
        for (int w = 0; w < 3; w++) pre += (w < wid) ? wtot[w] : 0u;
        const int incl = (int)(v + pre);
        const int excl = incl - (int)c;
        if (excl < krem && incl >= krem) {
            const unsigned long long binlo =
                (unsigned long long)lo + ((unsigned long long)tid << shift);
            if (shift == 0) {
                st->T = binlo;
                st->need = krem - excl;
                st->done = 1;
            } else if (incl == krem) {
                st->T = binlo + (1ull << shift);
                st->need = 0;
                st->done = 1;
            } else {
                st->lo = (unsigned)binlo;
                const unsigned long long nhi = binlo + (1ull << shift);
                st->hi = nhi < hi ? nhi : hi;
                st->krem = krem - excl;
            }
        }
        __syncthreads();
    }
}

// Phase 1: per-(row, 4096-segment) top-96. float4 loads (16B/lane; r6's
// scalar 4B loads were the bottleneck). Element index of key[j]:
// tid*4 + (j>>2)*1024 + (j&3). Selection is order-independent (radix count),
// tie-instance choice already atomic-nondeterministic.
__global__ __launch_bounds__(256) void topk_seg(
    const float* __restrict__ S, unsigned* __restrict__ K1key,
    int* __restrict__ K1idx)
{
    const int r = blockIdx.y, seg = blockIdx.x;
    const float* p = S + (size_t)r * NN + seg * TK_SEG;
    __shared__ unsigned hist[256];
    __shared__ unsigned wtot[4];
    __shared__ SelState st;
    __shared__ int cA, cB;
    const int tid = threadIdx.x;

    unsigned key[16];
#pragma unroll
    for (int j = 0; j < 4; j++) {
        float4 v = *(const float4*)(p + tid * 4 + j * 1024);
        key[j * 4 + 0] = fkey(v.x);
        key[j * 4 + 1] = fkey(v.y);
        key[j * 4 + 2] = fkey(v.z);
        key[j * 4 + 3] = fkey(v.w);
    }

    if (tid == 0) { cA = 0; cB = 0; }
    adaptive_select<16>(key, hist, wtot, &st, tid, NC);

    const unsigned long long T = st.T;
    const int need = st.need;
    const int cntLess = NC - need;
    const size_t obase = ((size_t)r * TK_SPLIT + seg) * NC;
#pragma unroll
    for (int j = 0; j < 16; j++) {
        const unsigned u = key[j];
        const int eidx = seg * TK_SEG + tid * 4 + (j >> 2) * 1024 + (j & 3);
        if ((unsigned long long)u < T) {
            const int pos = atomicAdd(&cA, 1);
            K1key[obase + pos] = u;
            K1idx[obase + pos] = eidx;
        } else if ((unsigned long long)u == T) {
            const int pos = atomicAdd(&cB, 1);
            if (pos < need) {
                K1key[obase + cntLess + pos] = u;
                K1idx[obase + cntLess + pos] = eidx;
            }
        }
    }
}

__global__ __launch_bounds__(256) void topk_merge(
    const unsigned* __restrict__ K1key, const int* __restrict__ K1idx,
    int* __restrict__ idx_out, float* __restrict__ val_out, int b0)
{
    const int r = blockIdx.x;
    const int b = b0 + r;
    __shared__ unsigned hist[256];
    __shared__ unsigned wtot[4];
    __shared__ SelState st;
    __shared__ int cA, cB;
    const int tid = threadIdx.x;
    const size_t ibase = (size_t)r * TK_CAND;

    unsigned key[6];
    int      kidx[6];
#pragma unroll
    for (int j = 0; j < 6; j++) {
        key[j]  = K1key[ibase + tid + j * 256];
        kidx[j] = K1idx[ibase + tid + j * 256];
    }

    if (tid == 0) { cA = 0; cB = 0; }
    adaptive_select<6>(key, hist, wtot, &st, tid, NC);

    const unsigned long long T = st.T;
    const int need = st.need;
    const int cntLess = NC - need;
#pragma unroll
    for (int j = 0; j < 6; j++) {
        const unsigned u = key[j];
        if ((unsigned long long)u < T) {
            const int pos = atomicAdd(&cA, 1);
            idx_out[b * NC + pos] = kidx[j];
            val_out[b * NC + pos] = inv_fkey(u);
        } else if ((unsigned long long)u == T) {
            const int pos = atomicAdd(&cB, 1);
            if (pos < need) {
                idx_out[b * NC + cntLess + pos] = kidx[j];
                val_out[b * NC + cntLess + pos] = inv_fkey(u);
            }
        }
    }
}

// ---------------------------------------------------------------------------
__global__ __launch_bounds__(128) void probs_kernel(
    const float* __restrict__ svals, float* __restrict__ probs)
{
    const int b = blockIdx.x;
    const int tid = threadIdx.x;
    __shared__ float red[128];
    const bool valid = tid < NC;
    float s = valid ? -svals[b * NC + tid] : -3.4e38f;
    red[tid] = s;
    __syncthreads();
#pragma unroll
    for (int off = 64; off; off >>= 1) {
        if (tid < off) red[tid] = fmaxf(red[tid], red[tid + off]);
        __syncthreads();
    }
    const float m = red[0];
    __syncthreads();
    float e = valid ? expf(s - m) : 0.f;
    red[tid] = e;
    __syncthreads();
#pragma unroll
    for (int off = 64; off; off >>= 1) {
        if (tid < off) red[tid] += red[tid + off];
        __syncthreads();
    }
    const float sum = red[0];
    if (valid) probs[b * NC + tid] = e / sum;
}

// ctx: xin given as planes (encoder-out x). Grid (BBD, 2): blockIdx.y picks
// a 256-wide d-half (r6: 128 blocks = 0.5/CU was the BW limiter; py reduce
// duplicated per half, cheap).
__global__ __launch_bounds__(256) void ctx_kernel(
    const float* __restrict__ VAL, const float* __restrict__ probs,
    const float* __restrict__ cand_y, const int* __restrict__ idx,
    const float* __restrict__ labW, const float* __restrict__ labb,
    const ushort* __restrict__ xinh, const ushort* __restrict__ xinl,
    float* __restrict__ xout, int b0)
{
    const int b_loc = blockIdx.x;
    const int b = b0 + b_loc;
    const int tid = threadIdx.x;
    __shared__ float pv[NC];
    __shared__ float red[256];
    float py_part = 0.f;
    if (tid < NC) {
        float p = probs[b * NC + tid];
        pv[tid] = p;
        py_part = p * cand_y[idx[b * NC + tid]];
    }
    red[tid] = py_part;
    __syncthreads();
#pragma unroll
    for (int off = 128; off; off >>= 1) {
        if (tid < off) red[tid] += red[tid + off];
        __syncthreads();
    }
    const float py = red[0];

    const int d = blockIdx.y * 256 + tid;   // one d per thread, 2 halves
    const float* vp = VAL + (size_t)b_loc * NC * ND + d;
    float acc = 0.f;
#pragma unroll 8
    for (int c = 0; c < NC; c++) acc += pv[c] * vp[(size_t)c * ND];
    float ctx = acc + py * labW[d] + labb[d];
    const size_t o = (size_t)b * ND + d;
    xout[o] = bf2f(xinh[o]) + bf2f(xinl[o]) + ctx;
}

__global__ __launch_bounds__(64) void head_kernel(
    const float* __restrict__ X, const float* __restrict__ hW,
    const float* __restrict__ hb, float* __restrict__ out)
{
    const int b = blockIdx.x;
    const int lane = threadIdx.x;
    const float* x = X + (size_t)b * ND;
    float acc = 0.f;
#pragma unroll
    for (int j = 0; j < 8; j++) {
        int d = lane + 64 * j;
        acc += x[d] * hW[d];
    }
#pragma unroll
    for (int off = 32; off; off >>= 1) acc += __shfl_down(acc, off);
    if (lane == 0) out[b] = acc + hb[0];
}

// ---------------------------------------------------------------------------
extern "C" void kernel_launch(void* const* d_in, const int* in_sizes, int n_in,
                              void* d_out, int out_size, void* d_ws, size_t ws_size,
                              hipStream_t stream)
{
    const float* x_num    = (const float*)d_in[0];
    const float* cand_num = (const float*)d_in[1];
    const float* cand_y   = (const float*)d_in[2];
    const float* lin_W    = (const float*)d_in[3];
    const float* lin_b    = (const float*)d_in[4];
    const float* e_W1     = (const float*)d_in[5];
    const float* e_b1     = (const float*)d_in[6];
    const float* e_W2     = (const float*)d_in[7];
    const float* e_b2     = (const float*)d_in[8];
    const float* mix_g    = (const float*)d_in[9];
    const float* mix_b    = (const float*)d_in[10];
    const float* K_W      = (const float*)d_in[11];
    const float* K_b      = (const float*)d_in[12];
    const float* lab_W    = (const float*)d_in[13];
    const float* lab_b    = (const float*)d_in[14];
    const float* T_W1     = (const float*)d_in[15];
    const float* T_b1     = (const float*)d_in[16];
    const float* T_W2     = (const float*)d_in[17];
    const float* p_ln_g   = (const float*)d_in[18];
    const float* p_ln_b   = (const float*)d_in[19];
    const float* p_W1     = (const float*)d_in[20];
    const float* p_b1     = (const float*)d_in[21];
    const float* p_W2     = (const float*)d_in[22];
    const float* p_b2     = (const float*)d_in[23];
    const float* h_ln_g   = (const float*)d_in[24];
    const float* h_ln_b   = (const float*)d_in[25];
    const float* h_W      = (const float*)d_in[26];
    const float* h_b      = (const float*)d_in[27];
    float* out = (float*)d_out;
    (void)in_sizes; (void)n_in; (void)out_size;

    const int NTOT = NN + NB;   // 66560 = 5*13312 = 8*8320

    // ---- workspace layout ----
    size_t off = 0;
    auto ralloc = [&](size_t bytes) -> void* {
        void* p = (char*)d_ws + off;
        off += (bytes + 255) & ~(size_t)255;
        return p;
    };
    auto falloc = [&](size_t n) -> float*  { return (float*)ralloc(n * 4); };
    auto ualloc = [&](size_t n) -> ushort* { return (ushort*)ralloc(n * 2); };

    // bf16 plane weights [N][K]
    ushort* WP_lin_h = ualloc((size_t)ND * NF);
    ushort* WP_lin_l = ualloc((size_t)ND * NF);
    ushort* WP_e1_h  = ualloc((size_t)NDB * ND);
    ushort* WP_e1_l  = ualloc((size_t)NDB * ND);
    ushort* WP_e2_h  = ualloc((size_t)ND * NDB);
    ushort* WP_e2_l  = ualloc((size_t)ND * NDB);
    ushort* WP_kw_h  = ualloc((size_t)ND * ND);
    ushort* WP_kw_l  = ualloc((size_t)ND * ND);
    ushort* WP_t1_h  = ualloc((size_t)NDB * ND);
    ushort* WP_t1_l  = ualloc((size_t)NDB * ND);
    ushort* WP_t2_h  = ualloc((size_t)ND * NDB);
    ushort* WP_t2_l  = ualloc((size_t)ND * NDB);
    ushort* WP_p1_h  = ualloc((size_t)NDB * ND);
    ushort* WP_p1_l  = ualloc((size_t)NDB * ND);
    ushort* WP_p2_h  = ualloc((size_t)ND * NDB);
    ushort* WP_p2_l  = ualloc((size_t)ND * NDB);

    // keys for candidates + x (x rows are the tail 1024)
    ushort* R_CKh = ualloc((size_t)NTOT * ND);
    ushort* R_CKl = ualloc((size_t)NTOT * ND);
    float*  R_sq  = falloc(NTOT);

    // persistent x activations
    ushort* X2h = ualloc((size_t)NB * ND);
    ushort* X2l = ualloc((size_t)NB * ND);
    ushort* Lxh = ualloc((size_t)NB * ND);
    ushort* Lxl = ualloc((size_t)NB * ND);
    ushort* Tph = ualloc((size_t)NB * NDB);
    ushort* Tpl = ualloc((size_t)NB * NDB);

    int*    R_idx = (int*)ralloc((size_t)NB * NC * 4);
    float*  R_ssel= falloc((size_t)NB * NC);
    float*  R_prob= falloc((size_t)NB * NC);
    float*  R_xupd= falloc((size_t)NB * ND);
    float*  R_lnx = falloc((size_t)NB * ND);
    float*  R_x2  = falloc((size_t)NB * ND);
    float*  R_lnx2= falloc((size_t)NB * ND);
    unsigned* K1key = (unsigned*)ralloc((size_t)BB_C * TK_CAND * 4);
    int*      K1idx = (int*)ralloc((size_t)BB_C * TK_CAND * 4);

    // ---- adaptive chunk: per-row scratch = H 2048B (in-place H2) +
    //      T 4096B (CN and G overlay the T region) = 6144 B.
    //      CH=13312 (5 chunks) if workspace allows, else 8320 (8 chunks).
    int CH;
    {
        const size_t remain = (ws_size > off) ? (ws_size - off) : 0;
        CH = (remain >= (size_t)13312 * 6144 + (size_t)(4u << 20)) ? 13312 : 8320;
    }
    size_t scr_bytes = (size_t)CH * 6144;
    const size_t scores_bytes = (size_t)BB_C * NN * 4;                  // 67.1 MB
    // values: DD [M][512]bf16 + TT [M][1024]bf16 + VAL [M][512]f32
    const size_t values_bytes = (size_t)BB_D * NC * (ND*2 + NDB*2 + ND*4); // 62.9 MB
    if (scr_bytes < scores_bytes) scr_bytes = scores_bytes;
    if (scr_bytes < values_bytes) scr_bytes = values_bytes;
    char* SCR = (char*)ralloc(scr_bytes);

    // ---- 0. weight prep (split-transpose to planes) ----
    auto sw = [&](const float* W, ushort* WTh, ushort* WTl, int K, int N) {
        split_wt_kernel<<<dim3((K * N + 255) / 256), dim3(256), 0, stream>>>(W, WTh, WTl, K, N);
    };
    sw(lin_W, WP_lin_h, WP_lin_l, NF, ND);
    sw(e_W1,  WP_e1_h,  WP_e1_l,  ND, NDB);
    sw(e_W2,  WP_e2_h,  WP_e2_l,  NDB, ND);
    sw(K_W,   WP_kw_h,  WP_kw_l,  ND, ND);
    sw(T_W1,  WP_t1_h,  WP_t1_l,  ND, NDB);
    sw(T_W2,  WP_t2_h,  WP_t2_l,  NDB, ND);
    sw(p_W1,  WP_p1_h,  WP_p1_l,  ND, NDB);
    sw(p_W2,  WP_p2_h,  WP_p2_l,  NDB, ND);

    auto gn64 = [&](const ushort* Ah, const ushort* Al, const ushort* Bh,
                    const ushort* Bl, const float* bias, const ushort* resh,
                    const ushort* resl, ushort* Ch, ushort* Cl,
                    int M, int Nn, int K, int relu) {
        gemm_ss_n64<<<dim3(Nn / 64, M / 128), dim3(256), 0, stream>>>(
            Ah, Al, Bh, Bl, bias, resh, resl, Ch, Cl, M, Nn, K, relu);
    };
    auto gsm = [&](const ushort* Ah, const ushort* Al, const ushort* Bh,
                   const ushort* Bl, const float* bias, const ushort* resh,
                   const ushort* resl, const float* resf, ushort* Ch,
                   ushort* Cl, float* outf, int M, int Nn, int K, int relu) {
        gemm_ss_small<<<dim3(Nn / 64, M / 64), dim3(256), 0, stream>>>(
            Ah, Al, Bh, Bl, bias, resh, resl, resf, Ch, Cl, outf, M, Nn, K, relu);
    };

    // ---- 1. unified encode: [candidates; x] in CH-row chunks ----
    // All four GEMMs on the 128x64 n64 tile (24 MFMA/kk density).
    {
        ushort* Hh = (ushort*)SCR;                     // [CH,512]
        ushort* Hl = Hh + (size_t)CH * ND;
        ushort* Th = Hl + (size_t)CH * ND;             // [CH,1024]
        ushort* Tl = Th + (size_t)CH * NDB;
        ushort* CNh = Th;   // overlay: CN dead once e1 writes T
        ushort* CNl = Tl;
        ushort* Gh  = Th;   // overlay: T dead after e2
        ushort* Gl  = Tl;

        for (int n0 = 0; n0 < NTOT; n0 += CH) {
            int candRows = NN - n0;
            if (candRows > CH) candRows = CH;
            if (candRows < 0)  candRows = 0;
            const int xRows = CH - candRows;   // 0 except last chunk (=NB)

            if (candRows)
                split_pl_kernel<<<dim3((candRows * NF + 255) / 256), dim3(256), 0, stream>>>(
                    cand_num + (size_t)n0 * NF, CNh, CNl, candRows * NF);
            if (xRows)
                split_pl_kernel<<<dim3((xRows * NF + 255) / 256), dim3(256), 0, stream>>>(
                    x_num, CNh + (size_t)candRows * NF, CNl + (size_t)candRows * NF,
                    xRows * NF);

            // lin: K=64 (single BK iter), grid 8 x CH/128
            gn64(CNh, CNl, WP_lin_h, WP_lin_l, lin_b, nullptr, nullptr,
                 Hh, Hl, CH, ND, NF, 0);
            // e1: grid 16 x CH/128 (1664 @ CH=13312)
            gn64(Hh, Hl, WP_e1_h, WP_e1_l, e_b1, nullptr, nullptr,
                 Th, Tl, CH, NDB, ND, 1);
            // e2 IN-PLACE: residual = H, output overwrites H
            gn64(Th, Tl, WP_e2_h, WP_e2_l, e_b2, Hh, Hl,
                 Hh, Hl, CH, ND, NDB, 0);

            if (xRows) {   // persist encoder-out planes for the x rows
                hipMemcpyAsync(X2h, Hh + (size_t)candRows * ND,
                               (size_t)NB * ND * 2, hipMemcpyDeviceToDevice, stream);
                hipMemcpyAsync(X2l, Hl + (size_t)candRows * ND,
                               (size_t)NB * ND * 2, hipMemcpyDeviceToDevice, stream);
            }

            ln_pl_kernel<<<dim3(CH / 4), dim3(256), 0, stream>>>(
                Hh, Hl, mix_g, mix_b, Gh, Gl);
            gn64(Gh, Gl, WP_kw_h, WP_kw_l, K_b, nullptr, nullptr,
                 R_CKh + (size_t)n0 * ND, R_CKl + (size_t)n0 * ND,
                 CH, ND, ND, 0);
            sqnorm_pl_kernel<<<dim3(CH / 4), dim3(256), 0, stream>>>(
                R_CKh + (size_t)n0 * ND, R_CKl + (size_t)n0 * ND, R_sq + n0);
        }
    }

    // x keys = tail rows of R_CK
    const ushort* kxh = R_CKh + (size_t)NN * ND;
    const ushort* kxl = R_CKl + (size_t)NN * ND;

    // ---- 2. scores (3-MFMA) + two-stage top-96 + softmax ----
    for (int b0 = 0; b0 < NB; b0 += BB_C) {
        float* S = (float*)SCR;
        gemm_ss<<<dim3(NN / 128, BB_C / 128), dim3(256), 0, stream>>>(
            kxh + (size_t)b0 * ND, kxl + (size_t)b0 * ND, R_CKh, R_CKl,
            R_sq, S, BB_C, NN, ND);
        topk_seg<<<dim3(TK_SPLIT, BB_C), dim3(256), 0, stream>>>(S, K1key, K1idx);
        topk_merge<<<dim3(BB_C), dim3(256), 0, stream>>>(K1key, K1idx,
                                                         R_idx, R_ssel, b0);
    }
    probs_kernel<<<dim3(NB), dim3(128), 0, stream>>>(R_ssel, R_prob);

    // ---- 3. values path: precomputed diff + two plain bf16 GEMMs ----
    for (int b0 = 0; b0 < NB; b0 += BB_D) {
        const int M = BB_D * NC;   // 12288
        ushort* DD  = (ushort*)SCR;                          // [M][512] bf16
        ushort* TT  = DD + (size_t)M * ND;                   // [M][1024] bf16
        float*  VAL = (float*)(TT + (size_t)M * NDB);        // [M][512] f32

        diff_pl_kernel<<<dim3((M * (ND / 8) + 255) / 256), dim3(256), 0, stream>>>(
            kxh + (size_t)b0 * ND, kxl + (size_t)b0 * ND,
            R_CKh, R_CKl, R_idx + b0 * NC, DD, M);
        // T1: DD @ t1^T (+bias, relu) -> TT bf16. grid 16x96 = 1536 blocks
        gemm_bf16_n64<<<dim3(NDB / 64, M / 128), dim3(256), 0, stream>>>(
            DD, WP_t1_h, T_b1, TT, nullptr, M, NDB, ND, 1);
        // T2: TT @ t2^T -> VAL f32. grid 8x96 = 768 blocks
        gemm_bf16_n64<<<dim3(ND / 64, M / 128), dim3(256), 0, stream>>>(
            TT, WP_t2_h, nullptr, nullptr, VAL, M, ND, NDB, 0);
        ctx_kernel<<<dim3(BB_D, 2), dim3(256), 0, stream>>>(
            VAL, R_prob, cand_y, R_idx, lab_W, lab_b, X2h, X2l, R_xupd, b0);
    }

    // ---- 4. predictor block + head (full 3-MFMA) ----
    ln_kernel<<<dim3(NB / 4), dim3(256), 0, stream>>>(R_xupd, p_ln_g, p_ln_b, R_lnx, 0);
    split_pl_kernel<<<dim3((NB * ND + 255) / 256), dim3(256), 0, stream>>>(
        R_lnx, Lxh, Lxl, NB * ND);
    gsm(Lxh, Lxl, WP_p1_h, WP_p1_l, p_b1, nullptr, nullptr, nullptr,
        Tph, Tpl, nullptr, NB, NDB, ND, 1);
    gsm(Tph, Tpl, WP_p2_h, WP_p2_l, p_b2, nullptr, nullptr, R_xupd,
        nullptr, nullptr, R_x2, NB, ND, NDB, 0);
    ln_kernel<<<dim3(NB / 4), dim3(256), 0, stream>>>(R_x2, h_ln_g, h_ln_b, R_lnx2, 1);
    head_kernel<<<dim3(NB), dim3(64), 0, stream>>>(R_lnx2, h_W, h_b, out);
}

// Round 9
// 2046.659 us; speedup vs baseline: 1.0484x; 1.0484x over previous
//
#include <hip/hip_runtime.h>

// Problem constants
#define NB   1024
#define NN   65536
#define NF   64
#define ND   512
#define NDB  1024
#define NC   96

// scores/topk chunk of B rows; values-path chunk
#define BB_C 256
#define BB_D 128

// top-k segmentation
#define TK_SPLIT 16
#define TK_SEG   (NN / TK_SPLIT)   // 4096
#define TK_CAND  (TK_SPLIT * NC)   // 1536

typedef unsigned short ushort;
typedef __attribute__((ext_vector_type(8))) short short8;
typedef __attribute__((ext_vector_type(4))) float floatx4;

__device__ __forceinline__ ushort f2bf(float f) {   // RNE f32->bf16
    unsigned u = __float_as_uint(f);
    u += 0x7fffu + ((u >> 16) & 1u);
    return (ushort)(u >> 16);
}
__device__ __forceinline__ float bf2f(ushort h) {
    return __uint_as_float(((unsigned)h) << 16);
}
// LDS plane: [m][k] bf16, k-stride 32, 16B-chunk XOR swizzle -> conflict-free
__device__ __forceinline__ int lds_off(int m, int c) {
    return m * 32 + (((c + (m >> 1)) & 3) << 3);
}

// async global->LDS 16B
__device__ __forceinline__ void gload16(const ushort* g, ushort* l)
{
    void* gv = (void*)g;
    void* lv = (void*)l;
    __builtin_amdgcn_global_load_lds(
        (__attribute__((address_space(1))) void*)gv,
        (__attribute__((address_space(3))) void*)lv, 16, 0, 0);
}

// XCD contiguous-slab swizzle (T1 variant): XCD i (= wg%8 launch order)
// processes the contiguous x-fastest tile range [i*nwg/8, (i+1)*nwg/8).
// Sibling col-tiles of one A row-panel become temporally-adjacent blocks on
// ONE XCD -> panel fetched ~once per L2 instead of 8x across XCDs.
// r4->r5: e2 FETCH 229->~110 MB class fix, wall -312 us. Bijective when
// nwg%8==0 (all remapped grids here); identity otherwise.
__device__ __forceinline__ void xcd_slab(int& bx, int& by)
{
    const int gx  = gridDim.x;
    const int nwg = gx * gridDim.y;
    int x = blockIdx.x, y = blockIdx.y;
    if (!(nwg & 7)) {
        const int wg = y * gx + x;
        const int t  = (wg & 7) * (nwg >> 3) + (wg >> 3);
        x = t % gx; y = t / gx;
    }
    bx = x; by = y;
}

// ---------------------------------------------------------------------------
// Split-plane MFMA GEMM (f32-emulating, 3 MFMA), NT, 128x128 tile.
// SCORES kernel. 1024-block grid -> 4 blocks/CU: cross-block overlap hides
// the per-iteration barrier drain (768-780 TF measured r5/r6 = structure
// ceiling; FETCH = 1x CK read). NOT slab-swizzled.
// ---------------------------------------------------------------------------
__global__ __launch_bounds__(256) void gemm_ss(
    const ushort* __restrict__ Ah_g, const ushort* __restrict__ Al_g,
    const ushort* __restrict__ Bh_g, const ushort* __restrict__ Bl_g,
    const float* __restrict__ scoresq, float* __restrict__ Sf,
    int M, int N, int K)
{
    __shared__ ushort Ah[128 * 32], Al[128 * 32];
    __shared__ ushort Bh[128 * 32], Bl[128 * 32];
    const int tid = threadIdx.x;
    const int lane = tid & 63, wid = tid >> 6;
    const int wm = (wid & 1) * 64, wn = (wid >> 1) * 64;
    const int lane15 = lane & 15, quad = lane >> 4;
    const int row0 = blockIdx.y * 128, col0 = blockIdx.x * 128;

    const int srow = tid >> 2;
    const int scl  = tid & 3;
    const int cp   = (scl - (srow >> 1)) & 3;
    const size_t ga0 = (size_t)(row0 + srow) * K + cp * 8;
    const size_t ga1 = (size_t)(row0 + 64 + srow) * K + cp * 8;
    const size_t gb0 = (size_t)(col0 + srow) * K + cp * 8;
    const size_t gb1 = (size_t)(col0 + 64 + srow) * K + cp * 8;
    const int l0 = tid * 8;
    const int l1 = 2048 + tid * 8;

    floatx4 acc[4][4];
#pragma unroll
    for (int i = 0; i < 4; i++)
#pragma unroll
        for (int j = 0; j < 4; j++) acc[i][j] = (floatx4){0.f, 0.f, 0.f, 0.f};

    for (int k0 = 0; k0 < K; k0 += 32) {
        __syncthreads();
        gload16(Ah_g + ga0 + k0, Ah + l0);
        gload16(Ah_g + ga1 + k0, Ah + l1);
        gload16(Al_g + ga0 + k0, Al + l0);
        gload16(Al_g + ga1 + k0, Al + l1);
        gload16(Bh_g + gb0 + k0, Bh + l0);
        gload16(Bh_g + gb1 + k0, Bh + l1);
        gload16(Bl_g + gb0 + k0, Bl + l0);
        gload16(Bl_g + gb1 + k0, Bl + l1);
        __syncthreads();

        short8 ah[4], al[4], bh[4], bl[4];
#pragma unroll
        for (int t = 0; t < 4; t++) {
            const int am = wm + t * 16 + lane15;
            const int bn = wn + t * 16 + lane15;
            ah[t] = *(const short8*)(Ah + lds_off(am, quad));
            al[t] = *(const short8*)(Al + lds_off(am, quad));
            bh[t] = *(const short8*)(Bh + lds_off(bn, quad));
            bl[t] = *(const short8*)(Bl + lds_off(bn, quad));
        }
#pragma unroll
        for (int i = 0; i < 4; i++)
#pragma unroll
            for (int j = 0; j < 4; j++) {
                acc[i][j] = __builtin_amdgcn_mfma_f32_16x16x32_bf16(ah[i], bh[j], acc[i][j], 0, 0, 0);
                acc[i][j] = __builtin_amdgcn_mfma_f32_16x16x32_bf16(ah[i], bl[j], acc[i][j], 0, 0, 0);
                acc[i][j] = __builtin_amdgcn_mfma_f32_16x16x32_bf16(al[i], bh[j], acc[i][j], 0, 0, 0);
            }
    }

    // C/D layout: col=lane&15, row=quad*4+reg  [m89]
#pragma unroll
    for (int i = 0; i < 4; i++)
#pragma unroll
        for (int j = 0; j < 4; j++) {
            const int gc = col0 + wn + j * 16 + lane15;
            const int rb = row0 + wm + i * 16 + quad * 4;
            const float sv = scoresq[gc];
#pragma unroll
            for (int r = 0; r < 4; r++) {
                const size_t o = (size_t)(rb + r) * N + gc;
                Sf[o] = sv - 2.f * acc[i][j][r];
            }
        }
}

// ---------------------------------------------------------------------------
// Split-plane GEMM, 128M x 64N tile, BK=64. Full 3-MFMA (B-lo required:
// dropping it measured absmax 0.047 -- do not re-try). Used for e1 ONLY:
// r7 measured moving e2/kw/lin here REGRESSED (+94 us): 48 KB LDS caps
// 3 blocks/CU and halves grid vs the 64^2 tile -- residency beats per-barrier
// MFMA density in this 2-barrier structure. Slab-swizzled.
// ---------------------------------------------------------------------------
__global__ __launch_bounds__(256) void gemm_ss_n64(
    const ushort* __restrict__ Ah_g, const ushort* __restrict__ Al_g,
    const ushort* __restrict__ Bh_g, const ushort* __restrict__ Bl_g,
    const float* __restrict__ bias,
    const ushort* resh, const ushort* resl,
    ushort* Ch, ushort* Cl,
    int M, int N, int K, int relu)
{
    __shared__ ushort Ah[128 * 64], Al[128 * 64];
    __shared__ ushort Bh[64 * 64], Bl[64 * 64];
    const int tid = threadIdx.x;
    const int lane = tid & 63, wid = tid >> 6;
    const int wm = wid * 32;
    const int lane15 = lane & 15, quad = lane >> 4;
    int bx, by; xcd_slab(bx, by);
    const int row0 = by * 128, col0 = bx * 64;

    const int srow = tid >> 2;
    const int scl  = tid & 3;
    const int cp   = (scl - (srow >> 1)) & 3;
    const size_t ga0 = (size_t)(row0 + srow) * K + cp * 8;
    const size_t ga1 = (size_t)(row0 + 64 + srow) * K + cp * 8;
    const size_t gb  = (size_t)(col0 + srow) * K + cp * 8;
    const int l0 = tid * 8;
    const int l1 = 2048 + tid * 8;

    floatx4 acc[2][4];
#pragma unroll
    for (int i = 0; i < 2; i++)
#pragma unroll
        for (int j = 0; j < 4; j++) acc[i][j] = (floatx4){0.f, 0.f, 0.f, 0.f};

    for (int k0 = 0; k0 < K; k0 += 64) {
        __syncthreads();
        gload16(Ah_g + ga0 + k0,      Ah + l0);
        gload16(Ah_g + ga1 + k0,      Ah + l1);
        gload16(Ah_g + ga0 + k0 + 32, Ah + 4096 + l0);
        gload16(Ah_g + ga1 + k0 + 32, Ah + 4096 + l1);
        gload16(Al_g + ga0 + k0,      Al + l0);
        gload16(Al_g + ga1 + k0,      Al + l1);
        gload16(Al_g + ga0 + k0 + 32, Al + 4096 + l0);
        gload16(Al_g + ga1 + k0 + 32, Al + 4096 + l1);
        gload16(Bh_g + gb + k0,       Bh + l0);
        gload16(Bh_g + gb + k0 + 32,  Bh + 2048 + l0);
        gload16(Bl_g + gb + k0,       Bl + l0);
        gload16(Bl_g + gb + k0 + 32,  Bl + 2048 + l0);
        __syncthreads();

#pragma unroll
        for (int kk = 0; kk < 2; kk++) {
            const int ao = kk * 4096, bo = kk * 2048;
            short8 ah[2], al[2], bh[4], bl[4];
#pragma unroll
            for (int t = 0; t < 2; t++) {
                const int am = wm + t * 16 + lane15;
                ah[t] = *(const short8*)(Ah + ao + lds_off(am, quad));
                al[t] = *(const short8*)(Al + ao + lds_off(am, quad));
            }
#pragma unroll
            for (int j = 0; j < 4; j++) {
                const int bn = j * 16 + lane15;
                bh[j] = *(const short8*)(Bh + bo + lds_off(bn, quad));
                bl[j] = *(const short8*)(Bl + bo + lds_off(bn, quad));
            }
#pragma unroll
            for (int i = 0; i < 2; i++)
#pragma unroll
                for (int j = 0; j < 4; j++) {
                    acc[i][j] = __builtin_amdgcn_mfma_f32_16x16x32_bf16(ah[i], bh[j], acc[i][j], 0, 0, 0);
                    acc[i][j] = __builtin_amdgcn_mfma_f32_16x16x32_bf16(ah[i], bl[j], acc[i][j], 0, 0, 0);
                    acc[i][j] = __builtin_amdgcn_mfma_f32_16x16x32_bf16(al[i], bh[j], acc[i][j], 0, 0, 0);
                }
        }
    }

#pragma unroll
    for (int i = 0; i < 2; i++)
#pragma unroll
        for (int j = 0; j < 4; j++) {
            const int gc = col0 + j * 16 + lane15;
            const int rb = row0 + wm + i * 16 + quad * 4;
            const float bv = bias ? bias[gc] : 0.f;
#pragma unroll
            for (int r = 0; r < 4; r++) {
                const size_t o = (size_t)(rb + r) * N + gc;
                float v = acc[i][j][r] + bv;
                if (resh) v += bf2f(resh[o]) + bf2f(resl[o]);
                if (relu) v = fmaxf(v, 0.f);
                ushort h = f2bf(v);
                Ch[o] = h;
                Cl[o] = f2bf(v - bf2f(h));
            }
        }
}

// ---------------------------------------------------------------------------
// Small-M split-plane GEMM: 64x64 tile, BK=64, full 3-MFMA. Flexible epi.
// NOTE: resh/resl/Ch/Cl are NOT __restrict__ -- e2 runs in-place (Ch==resh,
// same-thread read-before-write per element). 32 KB LDS -> 5 blocks/CU,
// big grids (1664 @ CH=13312): residency regime (r7 lesson). Slab-swizzled.
// ---------------------------------------------------------------------------
__global__ __launch_bounds__(256) void gemm_ss_small(
    const ushort* __restrict__ Ah_g, const ushort* __restrict__ Al_g,
    const ushort* __restrict__ Bh_g, const ushort* __restrict__ Bl_g,
    const float* __restrict__ bias,
    const ushort* resh, const ushort* resl,
    const float* resf,
    ushort* Ch, ushort* Cl,
    float* outf,
    int M, int N, int K, int relu)
{
    __shared__ ushort Ah[64 * 64], Al[64 * 64];
    __shared__ ushort Bh[64 * 64], Bl[64 * 64];
    const int tid = threadIdx.x;
    const int lane = tid & 63, wid = tid >> 6;
    const int wm = (wid & 1) * 32, wn = (wid >> 1) * 32;
    const int lane15 = lane & 15, quad = lane >> 4;
    int bx, by; xcd_slab(bx, by);
    const int row0 = by * 64, col0 = bx * 64;

    const int srow = tid >> 2;          // 0..63
    const int scl  = tid & 3;
    const int cp   = (scl - (srow >> 1)) & 3;
    const size_t ga = (size_t)(row0 + srow) * K + cp * 8;
    const size_t gb = (size_t)(col0 + srow) * K + cp * 8;
    const int l = tid * 8;

    floatx4 acc[2][2];
#pragma unroll
    for (int i = 0; i < 2; i++)
#pragma unroll
        for (int j = 0; j < 2; j++) acc[i][j] = (floatx4){0.f, 0.f, 0.f, 0.f};

    for (int k0 = 0; k0 < K; k0 += 64) {
        __syncthreads();
        gload16(Ah_g + ga + k0,      Ah + l);
        gload16(Ah_g + ga + k0 + 32, Ah + 2048 + l);
        gload16(Al_g + ga + k0,      Al + l);
        gload16(Al_g + ga + k0 + 32, Al + 2048 + l);
        gload16(Bh_g + gb + k0,      Bh + l);
        gload16(Bh_g + gb + k0 + 32, Bh + 2048 + l);
        gload16(Bl_g + gb + k0,      Bl + l);
        gload16(Bl_g + gb + k0 + 32, Bl + 2048 + l);
        __syncthreads();

#pragma unroll
        for (int kk = 0; kk < 2; kk++) {
            const int so = kk * 2048;
            short8 ah[2], al[2], bh[2], bl[2];
#pragma unroll
            for (int t = 0; t < 2; t++) {
                const int am = wm + t * 16 + lane15;
                const int bn = wn + t * 16 + lane15;
                ah[t] = *(const short8*)(Ah + so + lds_off(am, quad));
                al[t] = *(const short8*)(Al + so + lds_off(am, quad));
                bh[t] = *(const short8*)(Bh + so + lds_off(bn, quad));
                bl[t] = *(const short8*)(Bl + so + lds_off(bn, quad));
            }
#pragma unroll
            for (int i = 0; i < 2; i++)
#pragma unroll
                for (int j = 0; j < 2; j++) {
                    acc[i][j] = __builtin_amdgcn_mfma_f32_16x16x32_bf16(ah[i], bh[j], acc[i][j], 0, 0, 0);
                    acc[i][j] = __builtin_amdgcn_mfma_f32_16x16x32_bf16(ah[i], bl[j], acc[i][j], 0, 0, 0);
                    acc[i][j] = __builtin_amdgcn_mfma_f32_16x16x32_bf16(al[i], bh[j], acc[i][j], 0, 0, 0);
                }
        }
    }

#pragma unroll
    for (int i = 0; i < 2; i++)
#pragma unroll
        for (int j = 0; j < 2; j++) {
            const int gc = col0 + wn + j * 16 + lane15;
            const int rb = row0 + wm + i * 16 + quad * 4;
            const float bv = bias ? bias[gc] : 0.f;
#pragma unroll
            for (int r = 0; r < 4; r++) {
                const size_t o = (size_t)(rb + r) * N + gc;
                float v = acc[i][j][r] + bv;
                if (resh) v += bf2f(resh[o]) + bf2f(resl[o]);
                if (resf) v += resf[o];
                if (relu) v = fmaxf(v, 0.f);
                if (outf) outf[o] = v;
                if (Ch) {
                    ushort h = f2bf(v);
                    Ch[o] = h;
                    Cl[o] = f2bf(v - bf2f(h));
                }
            }
        }
}

// ---------------------------------------------------------------------------
// Values diff precompute: DD[r][:] = bf16((kx[b_loc] planes) - (ck[idx] planes))
// ---------------------------------------------------------------------------
__global__ __launch_bounds__(256) void diff_pl_kernel(
    const ushort* __restrict__ kxh, const ushort* __restrict__ kxl,  // +b0*ND
    const ushort* __restrict__ ckh, const ushort* __restrict__ ckl,
    const int* __restrict__ idx,                                     // +b0*NC
    ushort* __restrict__ DD, int Mrows)
{
    const int g = blockIdx.x * 256 + threadIdx.x;   // 8-elem group id
    if (g >= Mrows * (ND / 8)) return;
    const int r  = g >> 6;               // ND/8 = 64 groups per row
    const int d  = (g & 63) * 8;
    const int b_loc = r / NC;
    const int ci = idx[r];
    const size_t xb = (size_t)b_loc * ND + d;
    const size_t cb = (size_t)ci * ND + d;

    short8 xh = *(const short8*)(kxh + xb);
    short8 xl = *(const short8*)(kxl + xb);
    short8 ch = *(const short8*)(ckh + cb);
    short8 cl = *(const short8*)(ckl + cb);
    short8 dd;
#pragma unroll
    for (int i = 0; i < 8; i++) {
        const float a = bf2f((ushort)xh[i]) + bf2f((ushort)xl[i]);
        const float c = bf2f((ushort)ch[i]) + bf2f((ushort)cl[i]);
        dd[i] = (short)f2bf(a - c);
    }
    *(short8*)(DD + (size_t)r * ND + d) = dd;
}

// ---------------------------------------------------------------------------
// Plain bf16 GEMM: A [M][K], B hi plane [N][K]: C = A @ B^T (+bias, relu)
// 128M x 64N tile, BK=64. Output bf16 (Cbf) and/or f32 (Cf). Slab-swizzled.
// Used for values T1 (DD @ t1^T -> TT) and T2 (TT @ t2^T -> VAL).
// ---------------------------------------------------------------------------
__global__ __launch_bounds__(256) void gemm_bf16_n64(
    const ushort* __restrict__ A, const ushort* __restrict__ BTh,
    const float* __restrict__ bias,
    ushort* __restrict__ Cbf, float* __restrict__ Cf,
    int M, int N, int K, int relu)
{
    __shared__ ushort Ah[128 * 64];
    __shared__ ushort Bh[64 * 64];
    const int tid = threadIdx.x;
    const int lane = tid & 63, wid = tid >> 6;
    const int wm = wid * 32;
    const int lane15 = lane & 15, quad = lane >> 4;
    int bx, by; xcd_slab(bx, by);
    const int row0 = by * 128, col0 = bx * 64;

    const int srow = tid >> 2;
    const int scl  = tid & 3;
    const int cp   = (scl - (srow >> 1)) & 3;
    const size_t ga0 = (size_t)(row0 + srow) * K + cp * 8;
    const size_t ga1 = (size_t)(row0 + 64 + srow) * K + cp * 8;
    const size_t gb  = (size_t)(col0 + srow) * K + cp * 8;
    const int l0 = tid * 8, l1 = 2048 + tid * 8;

    floatx4 acc[2][4];
#pragma unroll
    for (int i = 0; i < 2; i++)
#pragma unroll
        for (int j = 0; j < 4; j++) acc[i][j] = (floatx4){0.f, 0.f, 0.f, 0.f};

    for (int k0 = 0; k0 < K; k0 += 64) {
        __syncthreads();
        gload16(A + ga0 + k0,      Ah + l0);
        gload16(A + ga1 + k0,      Ah + l1);
        gload16(A + ga0 + k0 + 32, Ah + 4096 + l0);
        gload16(A + ga1 + k0 + 32, Ah + 4096 + l1);
        gload16(BTh + gb + k0,      Bh + l0);
        gload16(BTh + gb + k0 + 32, Bh + 2048 + l0);
        __syncthreads();

#pragma unroll
        for (int kk = 0; kk < 2; kk++) {
            const int ao = kk * 4096, bo = kk * 2048;
            short8 ah[2], bh[4];
#pragma unroll
            for (int t = 0; t < 2; t++)
                ah[t] = *(const short8*)(Ah + ao + lds_off(wm + t * 16 + lane15, quad));
#pragma unroll
            for (int j = 0; j < 4; j++)
                bh[j] = *(const short8*)(Bh + bo + lds_off(j * 16 + lane15, quad));
#pragma unroll
            for (int i = 0; i < 2; i++)
#pragma unroll
                for (int j = 0; j < 4; j++)
                    acc[i][j] = __builtin_amdgcn_mfma_f32_16x16x32_bf16(ah[i], bh[j], acc[i][j], 0, 0, 0);
        }
    }

#pragma unroll
    for (int i = 0; i < 2; i++)
#pragma unroll
        for (int j = 0; j < 4; j++) {
            const int gc = col0 + j * 16 + lane15;
            const int rb = row0 + wm + i * 16 + quad * 4;
            const float bv = bias ? bias[gc] : 0.f;
#pragma unroll
            for (int rr = 0; rr < 4; rr++) {
                const size_t o = (size_t)(rb + rr) * N + gc;
                float v = acc[i][j][rr] + bv;
                if (relu) v = fmaxf(v, 0.f);
                if (Cbf) Cbf[o] = f2bf(v);
                if (Cf)  Cf[o] = v;
            }
        }
}

// ---------------------------------------------------------------------------
// Prep kernels
// ---------------------------------------------------------------------------
__global__ __launch_bounds__(256) void split_wt_kernel(
    const float* __restrict__ W, ushort* __restrict__ WTh,
    ushort* __restrict__ WTl, int K, int N)
{
    const int o = blockIdx.x * 256 + threadIdx.x;
    if (o < K * N) {
        const int n = o / K, k = o - n * K;
        const float x = W[(size_t)k * N + n];
        const ushort h = f2bf(x);
        WTh[o] = h;
        WTl[o] = f2bf(x - bf2f(h));
    }
}

__global__ __launch_bounds__(256) void split_pl_kernel(
    const float* __restrict__ X, ushort* __restrict__ Xh,
    ushort* __restrict__ Xl, int n)
{
    const int i = blockIdx.x * 256 + threadIdx.x;
    if (i < n) {
        const float x = X[i];
        const ushort h = f2bf(x);
        Xh[i] = h;
        Xl[i] = f2bf(x - bf2f(h));
    }
}

// ---------------------------------------------------------------------------
// LayerNorm rows of 512, f32 in / f32 out
// ---------------------------------------------------------------------------
__global__ __launch_bounds__(256) void ln_kernel(
    const float* __restrict__ X, const float* __restrict__ g,
    const float* __restrict__ b, float* __restrict__ Y, int relu)
{
    const int lane = threadIdx.x & 63;
    const int row  = blockIdx.x * 4 + (threadIdx.x >> 6);
    const float* x = X + (size_t)row * ND;
    const int d = lane * 8;

    float4 v0 = *(const float4*)(x + d);
    float4 v1 = *(const float4*)(x + d + 4);
    float s = v0.x + v0.y + v0.z + v0.w + v1.x + v1.y + v1.z + v1.w;
    float q = v0.x*v0.x + v0.y*v0.y + v0.z*v0.z + v0.w*v0.w
            + v1.x*v1.x + v1.y*v1.y + v1.z*v1.z + v1.w*v1.w;
#pragma unroll
    for (int off = 32; off; off >>= 1) {
        s += __shfl_down(s, off);
        q += __shfl_down(q, off);
    }
    s = __shfl(s, 0); q = __shfl(q, 0);
    const float mean = s * (1.f / ND);
    const float var  = q * (1.f / ND) - mean * mean;
    const float rs   = rsqrtf(var + 1e-5f);

    float4 g0 = *(const float4*)(g + d);
    float4 g1 = *(const float4*)(g + d + 4);
    float4 b0 = *(const float4*)(b + d);
    float4 b1 = *(const float4*)(b + d + 4);
    float4 o0, o1;
    o0.x = (v0.x - mean) * rs * g0.x + b0.x;
    o0.y = (v0.y - mean) * rs * g0.y + b0.y;
    o0.z = (v0.z - mean) * rs * g0.z + b0.z;
    o0.w = (v0.w - mean) * rs * g0.w + b0.w;
    o1.x = (v1.x - mean) * rs * g1.x + b1.x;
    o1.y = (v1.y - mean) * rs * g1.y + b1.y;
    o1.z = (v1.z - mean) * rs * g1.z + b1.z;
    o1.w = (v1.w - mean) * rs * g1.w + b1.w;
    if (relu) {
        o0.x = fmaxf(o0.x, 0.f); o0.y = fmaxf(o0.y, 0.f);
        o0.z = fmaxf(o0.z, 0.f); o0.w = fmaxf(o0.w, 0.f);
        o1.x = fmaxf(o1.x, 0.f); o1.y = fmaxf(o1.y, 0.f);
        o1.z = fmaxf(o1.z, 0.f); o1.w = fmaxf(o1.w, 0.f);
    }
    float* y = Y + (size_t)row * ND;
    *(float4*)(y + d)     = o0;
    *(float4*)(y + d + 4) = o1;
}

// LayerNorm rows of 512, planes in / planes out
__global__ __launch_bounds__(256) void ln_pl_kernel(
    const ushort* __restrict__ Xh, const ushort* __restrict__ Xl,
    const float* __restrict__ g, const float* __restrict__ b,
    ushort* __restrict__ Yh, ushort* __restrict__ Yl)
{
    const int lane = threadIdx.x & 63;
    const int row  = blockIdx.x * 4 + (threadIdx.x >> 6);
    const int d = lane * 8;
    const size_t base = (size_t)row * ND + d;

    short8 xh = *(const short8*)(Xh + base);
    short8 xl = *(const short8*)(Xl + base);
    float v[8];
#pragma unroll
    for (int i = 0; i < 8; i++) v[i] = bf2f((ushort)xh[i]) + bf2f((ushort)xl[i]);

    float s = 0.f, q = 0.f;
#pragma unroll
    for (int i = 0; i < 8; i++) { s += v[i]; q += v[i] * v[i]; }
#pragma unroll
    for (int off = 32; off; off >>= 1) {
        s += __shfl_down(s, off);
        q += __shfl_down(q, off);
    }
    s = __shfl(s, 0); q = __shfl(q, 0);
    const float mean = s * (1.f / ND);
    const float var  = q * (1.f / ND) - mean * mean;
    const float rs   = rsqrtf(var + 1e-5f);

    short8 yh, yl;
#pragma unroll
    for (int i = 0; i < 8; i++) {
        const float o = (v[i] - mean) * rs * g[d + i] + b[d + i];
        const ushort h = f2bf(o);
        yh[i] = (short)h;
        yl[i] = (short)f2bf(o - bf2f(h));
    }
    *(short8*)(Yh + base) = yh;
    *(short8*)(Yl + base) = yl;
}

__global__ __launch_bounds__(256) void sqnorm_pl_kernel(
    const ushort* __restrict__ Xh, const ushort* __restrict__ Xl,
    float* __restrict__ sq)
{
    const int lane = threadIdx.x & 63;
    const int row  = blockIdx.x * 4 + (threadIdx.x >> 6);
    const size_t base = (size_t)row * ND + lane * 8;
    short8 xh = *(const short8*)(Xh + base);
    short8 xl = *(const short8*)(Xl + base);
    float q = 0.f;
#pragma unroll
    for (int i = 0; i < 8; i++) {
        float v = bf2f((ushort)xh[i]) + bf2f((ushort)xl[i]);
        q += v * v;
    }
#pragma unroll
    for (int off = 32; off; off >>= 1) q += __shfl_down(q, off);
    if (lane == 0) sq[row] = q;
}

// ---------------------------------------------------------------------------
// Two-stage exact top-96: adaptive-range radix select.
// ---------------------------------------------------------------------------
__device__ __forceinline__ unsigned fkey(float f)
{
    unsigned u = __float_as_uint(f);
    return (u & 0x80000000u) ? ~u : (u | 0x80000000u);
}
__device__ __forceinline__ float inv_fkey(unsigned u)
{
    return __uint_as_float((u & 0x80000000u) ? (u & 0x7FFFFFFFu) : ~u);
}

struct SelState {
    unsigned lo;
    unsigned long long hi;   // exclusive
    int krem;
    int done;
    unsigned long long T;    // threshold
    int need;                // how many keys == T to take
};

template <int KPT>
__device__ __forceinline__ void adaptive_select(
    const unsigned (&key)[KPT], unsigned* hist, unsigned* wtot,
    SelState* st, int tid, int kwant)
{
    const int lane = tid & 63, wid = tid >> 6;

    unsigned mn = 0xFFFFFFFFu, mx = 0u;
#pragma unroll
    for (int j = 0; j < KPT; j++) {
        mn = min(mn, key[j]);
        mx = max(mx, key[j]);
    }
#pragma unroll
    for (int off = 32; off; off >>= 1) {
        mn = min(mn, (unsigned)__shfl_down((int)mn, off));
        mx = max(mx, (unsigned)__shfl_down((int)mx, off));
    }
    if (lane == 0) { hist[wid] = mn; hist[8 + wid] = mx; }
    if (tid == 0) st->done = 0;
    __syncthreads();
    if (tid == 0) {
        unsigned gmn = min(min(hist[0], hist[1]), min(hist[2], hist[3]));
        unsigned gmx = max(max(hist[8], hist[9]), max(hist[10], hist[11]));
        st->lo = gmn;
        st->hi = (unsigned long long)gmx + 1ull;
        st->krem = kwant;
    }
    __syncthreads();

    for (int iter = 0; iter < 6 && !st->done; iter++) {
        const unsigned lo = st->lo;
        const unsigned long long hi = st->hi;
        const int krem = st->krem;
        const unsigned long long span = hi - lo;
        int shift = 0;
        if (span > 256ull) {
            const int nb = 64 - __builtin_clzll(span - 1ull);
            shift = nb - 8;
        }
        hist[tid] = 0u;
        __syncthreads();
#pragma unroll
        for (int j = 0; j < KPT; j++) {
            const unsigned u = key[j];
            if (u >= lo && (unsigned long long)u < hi)
                atomicAdd(&hist[(u - lo) >> shift], 1u);
        }
        __syncthreads();
        const unsigned c = hist[tid];
        unsigned v = c;
#pragma unroll
        for (int off = 1; off < 64; off <<= 1) {
            const unsigned t = (unsigned)__shfl_up((int)v, off);
            if (lane >= off) v += t;
        }
        if (lane == 63) wtot[wid] = v;
        __syncthreads();
        unsigned pre = 0;
        for (int w = 0; w < 3; w++) pre += (w < wid) ? wtot[w] : 0u;
        const int incl = (int)(v + pre);
        const int excl = incl - (int)c;
        if (excl < krem && incl >= krem) {
            const unsigned long long binlo =
                (unsigned long long)lo + ((unsigned long long)tid << shift);
            if (shift == 0) {
                st->T = binlo;
                st->need = krem - excl;
                st->done = 1;
            } else if (incl == krem) {
                st->T = binlo + (1ull << shift);
                st->need = 0;
                st->done = 1;
            } else {
                st->lo = (unsigned)binlo;
                const unsigned long long nhi = binlo + (1ull << shift);
                st->hi = nhi < hi ? nhi : hi;
                st->krem = krem - excl;
            }
        }
        __syncthreads();
    }
}

// Phase 1: per-(row, 4096-segment) top-96. float4 loads (16B/lane).
// Element index of key[j]: tid*4 + (j>>2)*1024 + (j&3). Selection is
// order-independent (radix count).
__global__ __launch_bounds__(256) void topk_seg(
    const float* __restrict__ S, unsigned* __restrict__ K1key,
    int* __restrict__ K1idx)
{
    const int r = blockIdx.y, seg = blockIdx.x;
    const float* p = S + (size_t)r * NN + seg * TK_SEG;
    __shared__ unsigned hist[256];
    __shared__ unsigned wtot[4];
    __shared__ SelState st;
    __shared__ int cA, cB;
    const int tid = threadIdx.x;

    unsigned key[16];
#pragma unroll
    for (int j = 0; j < 4; j++) {
        float4 v = *(const float4*)(p + tid * 4 + j * 1024);
        key[j * 4 + 0] = fkey(v.x);
        key[j * 4 + 1] = fkey(v.y);
        key[j * 4 + 2] = fkey(v.z);
        key[j * 4 + 3] = fkey(v.w);
    }

    if (tid == 0) { cA = 0; cB = 0; }
    adaptive_select<16>(key, hist, wtot, &st, tid, NC);

    const unsigned long long T = st.T;
    const int need = st.need;
    const int cntLess = NC - need;
    const size_t obase = ((size_t)r * TK_SPLIT + seg) * NC;
#pragma unroll
    for (int j = 0; j < 16; j++) {
        const unsigned u = key[j];
        const int eidx = seg * TK_SEG + tid * 4 + (j >> 2) * 1024 + (j & 3);
        if ((unsigned long long)u < T) {
            const int pos = atomicAdd(&cA, 1);
            K1key[obase + pos] = u;
            K1idx[obase + pos] = eidx;
        } else if ((unsigned long long)u == T) {
            const int pos = atomicAdd(&cB, 1);
            if (pos < need) {
                K1key[obase + cntLess + pos] = u;
                K1idx[obase + cntLess + pos] = eidx;
            }
        }
    }
}

__global__ __launch_bounds__(256) void topk_merge(
    const unsigned* __restrict__ K1key, const int* __restrict__ K1idx,
    int* __restrict__ idx_out, float* __restrict__ val_out, int b0)
{
    const int r = blockIdx.x;
    const int b = b0 + r;
    __shared__ unsigned hist[256];
    __shared__ unsigned wtot[4];
    __shared__ SelState st;
    __shared__ int cA, cB;
    const int tid = threadIdx.x;
    const size_t ibase = (size_t)r * TK_CAND;

    unsigned key[6];
    int      kidx[6];
#pragma unroll
    for (int j = 0; j < 6; j++) {
        key[j]  = K1key[ibase + tid + j * 256];
        kidx[j] = K1idx[ibase + tid + j * 256];
    }

    if (tid == 0) { cA = 0; cB = 0; }
    adaptive_select<6>(key, hist, wtot, &st, tid, NC);

    const unsigned long long T = st.T;
    const int need = st.need;
    const int cntLess = NC - need;
#pragma unroll
    for (int j = 0; j < 6; j++) {
        const unsigned u = key[j];
        if ((unsigned long long)u < T) {
            const int pos = atomicAdd(&cA, 1);
            idx_out[b * NC + pos] = kidx[j];
            val_out[b * NC + pos] = inv_fkey(u);
        } else if ((unsigned long long)u == T) {
            const int pos = atomicAdd(&cB, 1);
            if (pos < need) {
                idx_out[b * NC + cntLess + pos] = kidx[j];
                val_out[b * NC + cntLess + pos] = inv_fkey(u);
            }
        }
    }
}

// ---------------------------------------------------------------------------
__global__ __launch_bounds__(128) void probs_kernel(
    const float* __restrict__ svals, float* __restrict__ probs)
{
    const int b = blockIdx.x;
    const int tid = threadIdx.x;
    __shared__ float red[128];
    const bool valid = tid < NC;
    float s = valid ? -svals[b * NC + tid] : -3.4e38f;
    red[tid] = s;
    __syncthreads();
#pragma unroll
    for (int off = 64; off; off >>= 1) {
        if (tid < off) red[tid] = fmaxf(red[tid], red[tid + off]);
        __syncthreads();
    }
    const float m = red[0];
    __syncthreads();
    float e = valid ? expf(s - m) : 0.f;
    red[tid] = e;
    __syncthreads();
#pragma unroll
    for (int off = 64; off; off >>= 1) {
        if (tid < off) red[tid] += red[tid + off];
        __syncthreads();
    }
    const float sum = red[0];
    if (valid) probs[b * NC + tid] = e / sum;
}

// ctx: xin given as planes (encoder-out x). Grid (BBD, 2): blockIdx.y picks
// a 256-wide d-half (256 blocks vs 128: better BW).
__global__ __launch_bounds__(256) void ctx_kernel(
    const float* __restrict__ VAL, const float* __restrict__ probs,
    const float* __restrict__ cand_y, const int* __restrict__ idx,
    const float* __restrict__ labW, const float* __restrict__ labb,
    const ushort* __restrict__ xinh, const ushort* __restrict__ xinl,
    float* __restrict__ xout, int b0)
{
    const int b_loc = blockIdx.x;
    const int b = b0 + b_loc;
    const int tid = threadIdx.x;
    __shared__ float pv[NC];
    __shared__ float red[256];
    float py_part = 0.f;
    if (tid < NC) {
        float p = probs[b * NC + tid];
        pv[tid] = p;
        py_part = p * cand_y[idx[b * NC + tid]];
    }
    red[tid] = py_part;
    __syncthreads();
#pragma unroll
    for (int off = 128; off; off >>= 1) {
        if (tid < off) red[tid] += red[tid + off];
        __syncthreads();
    }
    const float py = red[0];

    const int d = blockIdx.y * 256 + tid;   // one d per thread, 2 halves
    const float* vp = VAL + (size_t)b_loc * NC * ND + d;
    float acc = 0.f;
#pragma unroll 8
    for (int c = 0; c < NC; c++) acc += pv[c] * vp[(size_t)c * ND];
    float ctx = acc + py * labW[d] + labb[d];
    const size_t o = (size_t)b * ND + d;
    xout[o] = bf2f(xinh[o]) + bf2f(xinl[o]) + ctx;
}

__global__ __launch_bounds__(64) void head_kernel(
    const float* __restrict__ X, const float* __restrict__ hW,
    const float* __restrict__ hb, float* __restrict__ out)
{
    const int b = blockIdx.x;
    const int lane = threadIdx.x;
    const float* x = X + (size_t)b * ND;
    float acc = 0.f;
#pragma unroll
    for (int j = 0; j < 8; j++) {
        int d = lane + 64 * j;
        acc += x[d] * hW[d];
    }
#pragma unroll
    for (int off = 32; off; off >>= 1) acc += __shfl_down(acc, off);
    if (lane == 0) out[b] = acc + hb[0];
}

// ---------------------------------------------------------------------------
extern "C" void kernel_launch(void* const* d_in, const int* in_sizes, int n_in,
                              void* d_out, int out_size, void* d_ws, size_t ws_size,
                              hipStream_t stream)
{
    const float* x_num    = (const float*)d_in[0];
    const float* cand_num = (const float*)d_in[1];
    const float* cand_y   = (const float*)d_in[2];
    const float* lin_W    = (const float*)d_in[3];
    const float* lin_b    = (const float*)d_in[4];
    const float* e_W1     = (const float*)d_in[5];
    const float* e_b1     = (const float*)d_in[6];
    const float* e_W2     = (const float*)d_in[7];
    const float* e_b2     = (const float*)d_in[8];
    const float* mix_g    = (const float*)d_in[9];
    const float* mix_b    = (const float*)d_in[10];
    const float* K_W      = (const float*)d_in[11];
    const float* K_b      = (const float*)d_in[12];
    const float* lab_W    = (const float*)d_in[13];
    const float* lab_b    = (const float*)d_in[14];
    const float* T_W1     = (const float*)d_in[15];
    const float* T_b1     = (const float*)d_in[16];
    const float* T_W2     = (const float*)d_in[17];
    const float* p_ln_g   = (const float*)d_in[18];
    const float* p_ln_b   = (const float*)d_in[19];
    const float* p_W1     = (const float*)d_in[20];
    const float* p_b1     = (const float*)d_in[21];
    const float* p_W2     = (const float*)d_in[22];
    const float* p_b2     = (const float*)d_in[23];
    const float* h_ln_g   = (const float*)d_in[24];
    const float* h_ln_b   = (const float*)d_in[25];
    const float* h_W      = (const float*)d_in[26];
    const float* h_b      = (const float*)d_in[27];
    float* out = (float*)d_out;
    (void)in_sizes; (void)n_in; (void)out_size;

    const int NTOT = NN + NB;   // 66560 = 5*13312 = 8*8320

    // ---- workspace layout ----
    size_t off = 0;
    auto ralloc = [&](size_t bytes) -> void* {
        void* p = (char*)d_ws + off;
        off += (bytes + 255) & ~(size_t)255;
        return p;
    };
    auto falloc = [&](size_t n) -> float*  { return (float*)ralloc(n * 4); };
    auto ualloc = [&](size_t n) -> ushort* { return (ushort*)ralloc(n * 2); };

    // bf16 plane weights [N][K]
    ushort* WP_lin_h = ualloc((size_t)ND * NF);
    ushort* WP_lin_l = ualloc((size_t)ND * NF);
    ushort* WP_e1_h  = ualloc((size_t)NDB * ND);
    ushort* WP_e1_l  = ualloc((size_t)NDB * ND);
    ushort* WP_e2_h  = ualloc((size_t)ND * NDB);
    ushort* WP_e2_l  = ualloc((size_t)ND * NDB);
    ushort* WP_kw_h  = ualloc((size_t)ND * ND);
    ushort* WP_kw_l  = ualloc((size_t)ND * ND);
    ushort* WP_t1_h  = ualloc((size_t)NDB * ND);
    ushort* WP_t1_l  = ualloc((size_t)NDB * ND);
    ushort* WP_t2_h  = ualloc((size_t)ND * NDB);
    ushort* WP_t2_l  = ualloc((size_t)ND * NDB);
    ushort* WP_p1_h  = ualloc((size_t)NDB * ND);
    ushort* WP_p1_l  = ualloc((size_t)NDB * ND);
    ushort* WP_p2_h  = ualloc((size_t)ND * NDB);
    ushort* WP_p2_l  = ualloc((size_t)ND * NDB);

    // keys for candidates + x (x rows are the tail 1024)
    ushort* R_CKh = ualloc((size_t)NTOT * ND);
    ushort* R_CKl = ualloc((size_t)NTOT * ND);
    float*  R_sq  = falloc(NTOT);

    // persistent x activations
    ushort* X2h = ualloc((size_t)NB * ND);
    ushort* X2l = ualloc((size_t)NB * ND);
    ushort* Lxh = ualloc((size_t)NB * ND);
    ushort* Lxl = ualloc((size_t)NB * ND);
    ushort* Tph = ualloc((size_t)NB * NDB);
    ushort* Tpl = ualloc((size_t)NB * NDB);

    int*    R_idx = (int*)ralloc((size_t)NB * NC * 4);
    float*  R_ssel= falloc((size_t)NB * NC);
    float*  R_prob= falloc((size_t)NB * NC);
    float*  R_xupd= falloc((size_t)NB * ND);
    float*  R_lnx = falloc((size_t)NB * ND);
    float*  R_x2  = falloc((size_t)NB * ND);
    float*  R_lnx2= falloc((size_t)NB * ND);
    unsigned* K1key = (unsigned*)ralloc((size_t)BB_C * TK_CAND * 4);
    int*      K1idx = (int*)ralloc((size_t)BB_C * TK_CAND * 4);

    // ---- adaptive chunk: per-row scratch = H 2048B (in-place H2) +
    //      T 4096B (CN and G overlay the T region) = 6144 B.
    //      CH=13312 (5 chunks) if workspace allows, else 8320 (8 chunks).
    int CH;
    {
        const size_t remain = (ws_size > off) ? (ws_size - off) : 0;
        CH = (remain >= (size_t)13312 * 6144 + (size_t)(4u << 20)) ? 13312 : 8320;
    }
    size_t scr_bytes = (size_t)CH * 6144;
    const size_t scores_bytes = (size_t)BB_C * NN * 4;                  // 67.1 MB
    // values: DD [M][512]bf16 + TT [M][1024]bf16 + VAL [M][512]f32
    const size_t values_bytes = (size_t)BB_D * NC * (ND*2 + NDB*2 + ND*4); // 62.9 MB
    if (scr_bytes < scores_bytes) scr_bytes = scores_bytes;
    if (scr_bytes < values_bytes) scr_bytes = values_bytes;
    char* SCR = (char*)ralloc(scr_bytes);

    // ---- 0. weight prep (split-transpose to planes) ----
    auto sw = [&](const float* W, ushort* WTh, ushort* WTl, int K, int N) {
        split_wt_kernel<<<dim3((K * N + 255) / 256), dim3(256), 0, stream>>>(W, WTh, WTl, K, N);
    };
    sw(lin_W, WP_lin_h, WP_lin_l, NF, ND);
    sw(e_W1,  WP_e1_h,  WP_e1_l,  ND, NDB);
    sw(e_W2,  WP_e2_h,  WP_e2_l,  NDB, ND);
    sw(K_W,   WP_kw_h,  WP_kw_l,  ND, ND);
    sw(T_W1,  WP_t1_h,  WP_t1_l,  ND, NDB);
    sw(T_W2,  WP_t2_h,  WP_t2_l,  NDB, ND);
    sw(p_W1,  WP_p1_h,  WP_p1_l,  ND, NDB);
    sw(p_W2,  WP_p2_h,  WP_p2_l,  NDB, ND);

    auto gn64 = [&](const ushort* Ah, const ushort* Al, const ushort* Bh,
                    const ushort* Bl, const float* bias, const ushort* resh,
                    const ushort* resl, ushort* Ch, ushort* Cl,
                    int M, int Nn, int K, int relu) {
        gemm_ss_n64<<<dim3(Nn / 64, M / 128), dim3(256), 0, stream>>>(
            Ah, Al, Bh, Bl, bias, resh, resl, Ch, Cl, M, Nn, K, relu);
    };
    auto gsm = [&](const ushort* Ah, const ushort* Al, const ushort* Bh,
                   const ushort* Bl, const float* bias, const ushort* resh,
                   const ushort* resl, const float* resf, ushort* Ch,
                   ushort* Cl, float* outf, int M, int Nn, int K, int relu) {
        gemm_ss_small<<<dim3(Nn / 64, M / 64), dim3(256), 0, stream>>>(
            Ah, Al, Bh, Bl, bias, resh, resl, resf, Ch, Cl, outf, M, Nn, K, relu);
    };

    // ---- 1. unified encode: [candidates; x] in CH-row chunks ----
    // r6 configuration (best measured): lin/e2/kw on 64^2 gsm (residency),
    // e1 on 128x64 n64.
    {
        ushort* Hh = (ushort*)SCR;                     // [CH,512]
        ushort* Hl = Hh + (size_t)CH * ND;
        ushort* Th = Hl + (size_t)CH * ND;             // [CH,1024]
        ushort* Tl = Th + (size_t)CH * NDB;
        ushort* CNh = Th;   // overlay: CN dead once e1 writes T
        ushort* CNl = Tl;
        ushort* Gh  = Th;   // overlay: T dead after e2
        ushort* Gl  = Tl;

        for (int n0 = 0; n0 < NTOT; n0 += CH) {
            int candRows = NN - n0;
            if (candRows > CH) candRows = CH;
            if (candRows < 0)  candRows = 0;
            const int xRows = CH - candRows;   // 0 except last chunk (=NB)

            if (candRows)
                split_pl_kernel<<<dim3((candRows * NF + 255) / 256), dim3(256), 0, stream>>>(
                    cand_num + (size_t)n0 * NF, CNh, CNl, candRows * NF);
            if (xRows)
                split_pl_kernel<<<dim3((xRows * NF + 255) / 256), dim3(256), 0, stream>>>(
                    x_num, CNh + (size_t)candRows * NF, CNl + (size_t)candRows * NF,
                    xRows * NF);

            // lin: 64^2 tile, grid 8 x CH/64 (>=1040 blocks)
            gsm(CNh, CNl, WP_lin_h, WP_lin_l, lin_b, nullptr, nullptr, nullptr,
                Hh, Hl, nullptr, CH, ND, NF, 0);
            // e1: 128x64 tile, grid 16 x CH/128 (1664 @ CH=13312)
            gn64(Hh, Hl, WP_e1_h, WP_e1_l, e_b1, nullptr, nullptr,
                 Th, Tl, CH, NDB, ND, 1);
            // e2 IN-PLACE: residual = H, output overwrites H
            gsm(Th, Tl, WP_e2_h, WP_e2_l, e_b2, Hh, Hl, nullptr,
                Hh, Hl, nullptr, CH, ND, NDB, 0);

            if (xRows) {   // persist encoder-out planes for the x rows
                hipMemcpyAsync(X2h, Hh + (size_t)candRows * ND,
                               (size_t)NB * ND * 2, hipMemcpyDeviceToDevice, stream);
                hipMemcpyAsync(X2l, Hl + (size_t)candRows * ND,
                               (size_t)NB * ND * 2, hipMemcpyDeviceToDevice, stream);
            }

            ln_pl_kernel<<<dim3(CH / 4), dim3(256), 0, stream>>>(
                Hh, Hl, mix_g, mix_b, Gh, Gl);
            gsm(Gh, Gl, WP_kw_h, WP_kw_l, K_b, nullptr, nullptr, nullptr,
                R_CKh + (size_t)n0 * ND, R_CKl + (size_t)n0 * ND, nullptr,
                CH, ND, ND, 0);
            sqnorm_pl_kernel<<<dim3(CH / 4), dim3(256), 0, stream>>>(
                R_CKh + (size_t)n0 * ND, R_CKl + (size_t)n0 * ND, R_sq + n0);
        }
    }

    // x keys = tail rows of R_CK
    const ushort* kxh = R_CKh + (size_t)NN * ND;
    const ushort* kxl = R_CKl + (size_t)NN * ND;

    // ---- 2. scores (3-MFMA) + two-stage top-96 + softmax ----
    for (int b0 = 0; b0 < NB; b0 += BB_C) {
        float* S = (float*)SCR;
        gemm_ss<<<dim3(NN / 128, BB_C / 128), dim3(256), 0, stream>>>(
            kxh + (size_t)b0 * ND, kxl + (size_t)b0 * ND, R_CKh, R_CKl,
            R_sq, S, BB_C, NN, ND);
        topk_seg<<<dim3(TK_SPLIT, BB_C), dim3(256), 0, stream>>>(S, K1key, K1idx);
        topk_merge<<<dim3(BB_C), dim3(256), 0, stream>>>(K1key, K1idx,
                                                         R_idx, R_ssel, b0);
    }
    probs_kernel<<<dim3(NB), dim3(128), 0, stream>>>(R_ssel, R_prob);

    // ---- 3. values path: precomputed diff + two plain bf16 GEMMs ----
    for (int b0 = 0; b0 < NB; b0 += BB_D) {
        const int M = BB_D * NC;   // 12288
        ushort* DD  = (ushort*)SCR;                          // [M][512] bf16
        ushort* TT  = DD + (size_t)M * ND;                   // [M][1024] bf16
        float*  VAL = (float*)(TT + (size_t)M * NDB);        // [M][512] f32

        diff_pl_kernel<<<dim3((M * (ND / 8) + 255) / 256), dim3(256), 0, stream>>>(
            kxh + (size_t)b0 * ND, kxl + (size_t)b0 * ND,
            R_CKh, R_CKl, R_idx + b0 * NC, DD, M);
        // T1: DD @ t1^T (+bias, relu) -> TT bf16. grid 16x96 = 1536 blocks
        gemm_bf16_n64<<<dim3(NDB / 64, M / 128), dim3(256), 0, stream>>>(
            DD, WP_t1_h, T_b1, TT, nullptr, M, NDB, ND, 1);
        // T2: TT @ t2^T -> VAL f32. grid 8x96 = 768 blocks
        gemm_bf16_n64<<<dim3(ND / 64, M / 128), dim3(256), 0, stream>>>(
            TT, WP_t2_h, nullptr, nullptr, VAL, M, ND, NDB, 0);
        ctx_kernel<<<dim3(BB_D, 2), dim3(256), 0, stream>>>(
            VAL, R_prob, cand_y, R_idx, lab_W, lab_b, X2h, X2l, R_xupd, b0);
    }

    // ---- 4. predictor block + head (full 3-MFMA) ----
    ln_kernel<<<dim3(NB / 4), dim3(256), 0, stream>>>(R_xupd, p_ln_g, p_ln_b, R_lnx, 0);
    split_pl_kernel<<<dim3((NB * ND + 255) / 256), dim3(256), 0, stream>>>(
        R_lnx, Lxh, Lxl, NB * ND);
    gsm(Lxh, Lxl, WP_p1_h, WP_p1_l, p_b1, nullptr, nullptr, nullptr,
        Tph, Tpl, nullptr, NB, NDB, ND, 1);
    gsm(Tph, Tpl, WP_p2_h, WP_p2_l, p_b2, nullptr, nullptr, R_xupd,
        nullptr, nullptr, R_x2, NB, ND, NDB, 0);
    ln_kernel<<<dim3(NB / 4), dim3(256), 0, stream>>>(R_x2, h_ln_g, h_ln_b, R_lnx2, 1);
    head_kernel<<<dim3(NB), dim3(64), 0, stream>>>(R_lnx2, h_W, h_b, out);
}

// Round 10
// 2013.638 us; speedup vs baseline: 1.0656x; 1.0164x over previous
//
#include <hip/hip_runtime.h>

// Problem constants
#define NB   1024
#define NN   65536
#define NF   64
#define ND   512
#define NDB  1024
#define NC   96

// scores/topk chunk of B rows; values-path chunk
#define BB_C 256
#define BB_D 128

// top-k segmentation
#define TK_SPLIT 16
#define TK_SEG   (NN / TK_SPLIT)   // 4096
#define TK_CAND  (TK_SPLIT * NC)   // 1536

typedef unsigned short ushort;
typedef __attribute__((ext_vector_type(8))) short short8;
typedef __attribute__((ext_vector_type(4))) float floatx4;

__device__ __forceinline__ ushort f2bf(float f) {   // RNE f32->bf16
    unsigned u = __float_as_uint(f);
    u += 0x7fffu + ((u >> 16) & 1u);
    return (ushort)(u >> 16);
}
__device__ __forceinline__ float bf2f(ushort h) {
    return __uint_as_float(((unsigned)h) << 16);
}
// LDS plane: [m][k] bf16, k-stride 32, 16B-chunk XOR swizzle -> conflict-free
__device__ __forceinline__ int lds_off(int m, int c) {
    return m * 32 + (((c + (m >> 1)) & 3) << 3);
}

// async global->LDS 16B
__device__ __forceinline__ void gload16(const ushort* g, ushort* l)
{
    void* gv = (void*)g;
    void* lv = (void*)l;
    __builtin_amdgcn_global_load_lds(
        (__attribute__((address_space(1))) void*)gv,
        (__attribute__((address_space(3))) void*)lv, 16, 0, 0);
}

// XCD contiguous-slab swizzle (T1 variant): XCD i (= wg%8 launch order)
// processes the contiguous x-fastest tile range [i*nwg/8, (i+1)*nwg/8).
// Sibling col-tiles of one A row-panel become temporally-adjacent blocks on
// ONE XCD -> panel fetched ~once per L2 instead of 8x across XCDs.
// r4->r5: e2 FETCH 229->~110 MB class fix, wall -312 us. Bijective when
// nwg%8==0 (all remapped grids here); identity otherwise.
__device__ __forceinline__ void xcd_slab(int& bx, int& by)
{
    const int gx  = gridDim.x;
    const int nwg = gx * gridDim.y;
    int x = blockIdx.x, y = blockIdx.y;
    if (!(nwg & 7)) {
        const int wg = y * gx + x;
        const int t  = (wg & 7) * (nwg >> 3) + (wg >> 3);
        x = t % gx; y = t / gx;
    }
    bx = x; by = y;
}

// ---------------------------------------------------------------------------
// Split-plane MFMA GEMM (f32-emulating, 3 MFMA), NT, 128x128 tile.
// SCORES kernel. 1024-block grid -> 4 blocks/CU: cross-block overlap hides
// the per-iteration barrier drain (768-780 TF measured r5/r6/r9 = structure
// ceiling; FETCH = 1x CK read). NOT slab-swizzled.
// ---------------------------------------------------------------------------
__global__ __launch_bounds__(256) void gemm_ss(
    const ushort* __restrict__ Ah_g, const ushort* __restrict__ Al_g,
    const ushort* __restrict__ Bh_g, const ushort* __restrict__ Bl_g,
    const float* __restrict__ scoresq, float* __restrict__ Sf,
    int M, int N, int K)
{
    __shared__ ushort Ah[128 * 32], Al[128 * 32];
    __shared__ ushort Bh[128 * 32], Bl[128 * 32];
    const int tid = threadIdx.x;
    const int lane = tid & 63, wid = tid >> 6;
    const int wm = (wid & 1) * 64, wn = (wid >> 1) * 64;
    const int lane15 = lane & 15, quad = lane >> 4;
    const int row0 = blockIdx.y * 128, col0 = blockIdx.x * 128;

    const int srow = tid >> 2;
    const int scl  = tid & 3;
    const int cp   = (scl - (srow >> 1)) & 3;
    const size_t ga0 = (size_t)(row0 + srow) * K + cp * 8;
    const size_t ga1 = (size_t)(row0 + 64 + srow) * K + cp * 8;
    const size_t gb0 = (size_t)(col0 + srow) * K + cp * 8;
    const size_t gb1 = (size_t)(col0 + 64 + srow) * K + cp * 8;
    const int l0 = tid * 8;
    const int l1 = 2048 + tid * 8;

    floatx4 acc[4][4];
#pragma unroll
    for (int i = 0; i < 4; i++)
#pragma unroll
        for (int j = 0; j < 4; j++) acc[i][j] = (floatx4){0.f, 0.f, 0.f, 0.f};

    for (int k0 = 0; k0 < K; k0 += 32) {
        __syncthreads();
        gload16(Ah_g + ga0 + k0, Ah + l0);
        gload16(Ah_g + ga1 + k0, Ah + l1);
        gload16(Al_g + ga0 + k0, Al + l0);
        gload16(Al_g + ga1 + k0, Al + l1);
        gload16(Bh_g + gb0 + k0, Bh + l0);
        gload16(Bh_g + gb1 + k0, Bh + l1);
        gload16(Bl_g + gb0 + k0, Bl + l0);
        gload16(Bl_g + gb1 + k0, Bl + l1);
        __syncthreads();

        short8 ah[4], al[4], bh[4], bl[4];
#pragma unroll
        for (int t = 0; t < 4; t++) {
            const int am = wm + t * 16 + lane15;
            const int bn = wn + t * 16 + lane15;
            ah[t] = *(const short8*)(Ah + lds_off(am, quad));
            al[t] = *(const short8*)(Al + lds_off(am, quad));
            bh[t] = *(const short8*)(Bh + lds_off(bn, quad));
            bl[t] = *(const short8*)(Bl + lds_off(bn, quad));
        }
#pragma unroll
        for (int i = 0; i < 4; i++)
#pragma unroll
            for (int j = 0; j < 4; j++) {
                acc[i][j] = __builtin_amdgcn_mfma_f32_16x16x32_bf16(ah[i], bh[j], acc[i][j], 0, 0, 0);
                acc[i][j] = __builtin_amdgcn_mfma_f32_16x16x32_bf16(ah[i], bl[j], acc[i][j], 0, 0, 0);
                acc[i][j] = __builtin_amdgcn_mfma_f32_16x16x32_bf16(al[i], bh[j], acc[i][j], 0, 0, 0);
            }
    }

    // C/D layout: col=lane&15, row=quad*4+reg  [m89]
#pragma unroll
    for (int i = 0; i < 4; i++)
#pragma unroll
        for (int j = 0; j < 4; j++) {
            const int gc = col0 + wn + j * 16 + lane15;
            const int rb = row0 + wm + i * 16 + quad * 4;
            const float sv = scoresq[gc];
#pragma unroll
            for (int r = 0; r < 4; r++) {
                const size_t o = (size_t)(rb + r) * N + gc;
                Sf[o] = sv - 2.f * acc[i][j][r];
            }
        }
}

// ---------------------------------------------------------------------------
// Split-plane GEMM, 128M x 64N tile, BK=64. Full 3-MFMA (B-lo required:
// dropping it measured absmax 0.047 -- do not re-try). Used for e1 ONLY:
// r7 measured moving e2/kw/lin here REGRESSED (+94 us): 48 KB LDS caps
// 3 blocks/CU and halves grid vs the 64^2 tile -- residency beats per-barrier
// MFMA density in this 2-barrier structure. Slab-swizzled.
// ---------------------------------------------------------------------------
__global__ __launch_bounds__(256) void gemm_ss_n64(
    const ushort* __restrict__ Ah_g, const ushort* __restrict__ Al_g,
    const ushort* __restrict__ Bh_g, const ushort* __restrict__ Bl_g,
    const float* __restrict__ bias,
    const ushort* resh, const ushort* resl,
    ushort* Ch, ushort* Cl,
    int M, int N, int K, int relu)
{
    __shared__ ushort Ah[128 * 64], Al[128 * 64];
    __shared__ ushort Bh[64 * 64], Bl[64 * 64];
    const int tid = threadIdx.x;
    const int lane = tid & 63, wid = tid >> 6;
    const int wm = wid * 32;
    const int lane15 = lane & 15, quad = lane >> 4;
    int bx, by; xcd_slab(bx, by);
    const int row0 = by * 128, col0 = bx * 64;

    const int srow = tid >> 2;
    const int scl  = tid & 3;
    const int cp   = (scl - (srow >> 1)) & 3;
    const size_t ga0 = (size_t)(row0 + srow) * K + cp * 8;
    const size_t ga1 = (size_t)(row0 + 64 + srow) * K + cp * 8;
    const size_t gb  = (size_t)(col0 + srow) * K + cp * 8;
    const int l0 = tid * 8;
    const int l1 = 2048 + tid * 8;

    floatx4 acc[2][4];
#pragma unroll
    for (int i = 0; i < 2; i++)
#pragma unroll
        for (int j = 0; j < 4; j++) acc[i][j] = (floatx4){0.f, 0.f, 0.f, 0.f};

    for (int k0 = 0; k0 < K; k0 += 64) {
        __syncthreads();
        gload16(Ah_g + ga0 + k0,      Ah + l0);
        gload16(Ah_g + ga1 + k0,      Ah + l1);
        gload16(Ah_g + ga0 + k0 + 32, Ah + 4096 + l0);
        gload16(Ah_g + ga1 + k0 + 32, Ah + 4096 + l1);
        gload16(Al_g + ga0 + k0,      Al + l0);
        gload16(Al_g + ga1 + k0,      Al + l1);
        gload16(Al_g + ga0 + k0 + 32, Al + 4096 + l0);
        gload16(Al_g + ga1 + k0 + 32, Al + 4096 + l1);
        gload16(Bh_g + gb + k0,       Bh + l0);
        gload16(Bh_g + gb + k0 + 32,  Bh + 2048 + l0);
        gload16(Bl_g + gb + k0,       Bl + l0);
        gload16(Bl_g + gb + k0 + 32,  Bl + 2048 + l0);
        __syncthreads();

#pragma unroll
        for (int kk = 0; kk < 2; kk++) {
            const int ao = kk * 4096, bo = kk * 2048;
            short8 ah[2], al[2], bh[4], bl[4];
#pragma unroll
            for (int t = 0; t < 2; t++) {
                const int am = wm + t * 16 + lane15;
                ah[t] = *(const short8*)(Ah + ao + lds_off(am, quad));
                al[t] = *(const short8*)(Al + ao + lds_off(am, quad));
            }
#pragma unroll
            for (int j = 0; j < 4; j++) {
                const int bn = j * 16 + lane15;
                bh[j] = *(const short8*)(Bh + bo + lds_off(bn, quad));
                bl[j] = *(const short8*)(Bl + bo + lds_off(bn, quad));
            }
#pragma unroll
            for (int i = 0; i < 2; i++)
#pragma unroll
                for (int j = 0; j < 4; j++) {
                    acc[i][j] = __builtin_amdgcn_mfma_f32_16x16x32_bf16(ah[i], bh[j], acc[i][j], 0, 0, 0);
                    acc[i][j] = __builtin_amdgcn_mfma_f32_16x16x32_bf16(ah[i], bl[j], acc[i][j], 0, 0, 0);
                    acc[i][j] = __builtin_amdgcn_mfma_f32_16x16x32_bf16(al[i], bh[j], acc[i][j], 0, 0, 0);
                }
        }
    }

#pragma unroll
    for (int i = 0; i < 2; i++)
#pragma unroll
        for (int j = 0; j < 4; j++) {
            const int gc = col0 + j * 16 + lane15;
            const int rb = row0 + wm + i * 16 + quad * 4;
            const float bv = bias ? bias[gc] : 0.f;
#pragma unroll
            for (int r = 0; r < 4; r++) {
                const size_t o = (size_t)(rb + r) * N + gc;
                float v = acc[i][j][r] + bv;
                if (resh) v += bf2f(resh[o]) + bf2f(resl[o]);
                if (relu) v = fmaxf(v, 0.f);
                ushort h = f2bf(v);
                Ch[o] = h;
                Cl[o] = f2bf(v - bf2f(h));
            }
        }
}

// ---------------------------------------------------------------------------
// Small-M split-plane GEMM: 64x64 tile, BK=64, full 3-MFMA. Flexible epi.
// NOTE: resh/resl/Ch/Cl are NOT __restrict__ -- e2 runs in-place (Ch==resh,
// same-thread read-before-write per element). 32 KB LDS -> 5 blocks/CU,
// big grids (1664 @ CH=13312): residency regime (r7 lesson). Slab-swizzled.
// ---------------------------------------------------------------------------
__global__ __launch_bounds__(256) void gemm_ss_small(
    const ushort* __restrict__ Ah_g, const ushort* __restrict__ Al_g,
    const ushort* __restrict__ Bh_g, const ushort* __restrict__ Bl_g,
    const float* __restrict__ bias,
    const ushort* resh, const ushort* resl,
    const float* resf,
    ushort* Ch, ushort* Cl,
    float* outf,
    int M, int N, int K, int relu)
{
    __shared__ ushort Ah[64 * 64], Al[64 * 64];
    __shared__ ushort Bh[64 * 64], Bl[64 * 64];
    const int tid = threadIdx.x;
    const int lane = tid & 63, wid = tid >> 6;
    const int wm = (wid & 1) * 32, wn = (wid >> 1) * 32;
    const int lane15 = lane & 15, quad = lane >> 4;
    int bx, by; xcd_slab(bx, by);
    const int row0 = by * 64, col0 = bx * 64;

    const int srow = tid >> 2;          // 0..63
    const int scl  = tid & 3;
    const int cp   = (scl - (srow >> 1)) & 3;
    const size_t ga = (size_t)(row0 + srow) * K + cp * 8;
    const size_t gb = (size_t)(col0 + srow) * K + cp * 8;
    const int l = tid * 8;

    floatx4 acc[2][2];
#pragma unroll
    for (int i = 0; i < 2; i++)
#pragma unroll
        for (int j = 0; j < 2; j++) acc[i][j] = (floatx4){0.f, 0.f, 0.f, 0.f};

    for (int k0 = 0; k0 < K; k0 += 64) {
        __syncthreads();
        gload16(Ah_g + ga + k0,      Ah + l);
        gload16(Ah_g + ga + k0 + 32, Ah + 2048 + l);
        gload16(Al_g + ga + k0,      Al + l);
        gload16(Al_g + ga + k0 + 32, Al + 2048 + l);
        gload16(Bh_g + gb + k0,      Bh + l);
        gload16(Bh_g + gb + k0 + 32, Bh + 2048 + l);
        gload16(Bl_g + gb + k0,      Bl + l);
        gload16(Bl_g + gb + k0 + 32, Bl + 2048 + l);
        __syncthreads();

#pragma unroll
        for (int kk = 0; kk < 2; kk++) {
            const int so = kk * 2048;
            short8 ah[2], al[2], bh[2], bl[2];
#pragma unroll
            for (int t = 0; t < 2; t++) {
                const int am = wm + t * 16 + lane15;
                const int bn = wn + t * 16 + lane15;
                ah[t] = *(const short8*)(Ah + so + lds_off(am, quad));
                al[t] = *(const short8*)(Al + so + lds_off(am, quad));
                bh[t] = *(const short8*)(Bh + so + lds_off(bn, quad));
                bl[t] = *(const short8*)(Bl + so + lds_off(bn, quad));
            }
#pragma unroll
            for (int i = 0; i < 2; i++)
#pragma unroll
                for (int j = 0; j < 2; j++) {
                    acc[i][j] = __builtin_amdgcn_mfma_f32_16x16x32_bf16(ah[i], bh[j], acc[i][j], 0, 0, 0);
                    acc[i][j] = __builtin_amdgcn_mfma_f32_16x16x32_bf16(ah[i], bl[j], acc[i][j], 0, 0, 0);
                    acc[i][j] = __builtin_amdgcn_mfma_f32_16x16x32_bf16(al[i], bh[j], acc[i][j], 0, 0, 0);
                }
        }
    }

#pragma unroll
    for (int i = 0; i < 2; i++)
#pragma unroll
        for (int j = 0; j < 2; j++) {
            const int gc = col0 + wn + j * 16 + lane15;
            const int rb = row0 + wm + i * 16 + quad * 4;
            const float bv = bias ? bias[gc] : 0.f;
#pragma unroll
            for (int r = 0; r < 4; r++) {
                const size_t o = (size_t)(rb + r) * N + gc;
                float v = acc[i][j][r] + bv;
                if (resh) v += bf2f(resh[o]) + bf2f(resl[o]);
                if (resf) v += resf[o];
                if (relu) v = fmaxf(v, 0.f);
                if (outf) outf[o] = v;
                if (Ch) {
                    ushort h = f2bf(v);
                    Ch[o] = h;
                    Cl[o] = f2bf(v - bf2f(h));
                }
            }
        }
}

// ---------------------------------------------------------------------------
// Values diff precompute: DD[r][:] = bf16((kx[b_loc] planes) - (ck[idx] planes))
// ---------------------------------------------------------------------------
__global__ __launch_bounds__(256) void diff_pl_kernel(
    const ushort* __restrict__ kxh, const ushort* __restrict__ kxl,  // +b0*ND
    const ushort* __restrict__ ckh, const ushort* __restrict__ ckl,
    const int* __restrict__ idx,                                     // +b0*NC
    ushort* __restrict__ DD, int Mrows)
{
    const int g = blockIdx.x * 256 + threadIdx.x;   // 8-elem group id
    if (g >= Mrows * (ND / 8)) return;
    const int r  = g >> 6;               // ND/8 = 64 groups per row
    const int d  = (g & 63) * 8;
    const int b_loc = r / NC;
    const int ci = idx[r];
    const size_t xb = (size_t)b_loc * ND + d;
    const size_t cb = (size_t)ci * ND + d;

    short8 xh = *(const short8*)(kxh + xb);
    short8 xl = *(const short8*)(kxl + xb);
    short8 ch = *(const short8*)(ckh + cb);
    short8 cl = *(const short8*)(ckl + cb);
    short8 dd;
#pragma unroll
    for (int i = 0; i < 8; i++) {
        const float a = bf2f((ushort)xh[i]) + bf2f((ushort)xl[i]);
        const float c = bf2f((ushort)ch[i]) + bf2f((ushort)cl[i]);
        dd[i] = (short)f2bf(a - c);
    }
    *(short8*)(DD + (size_t)r * ND + d) = dd;
}

// ---------------------------------------------------------------------------
// Plain bf16 GEMM, 128x128 tile, BK=32 (m97 structure: 16 MFMA per 16 KB
// staged -- 2x the per-barrier MFMA density of the n64 tile). Used for
// values T1 (grid 8x96 = 768 blocks = 3/CU, residency regime OK).
// Same ascending-K=32 accumulation order as the n64 version -> bitwise
// identical output. bias+relu epilogue, bf16 out. Slab-swizzled.
// ---------------------------------------------------------------------------
__global__ __launch_bounds__(256) void gemm_bf16_128(
    const ushort* __restrict__ A, const ushort* __restrict__ BTh,
    const float* __restrict__ bias,
    ushort* __restrict__ Cbf,
    int M, int N, int K, int relu)
{
    __shared__ ushort Ah[128 * 32];
    __shared__ ushort Bh[128 * 32];
    const int tid = threadIdx.x;
    const int lane = tid & 63, wid = tid >> 6;
    const int wm = (wid & 1) * 64, wn = (wid >> 1) * 64;
    const int lane15 = lane & 15, quad = lane >> 4;
    int bx, by; xcd_slab(bx, by);
    const int row0 = by * 128, col0 = bx * 128;

    const int srow = tid >> 2;
    const int scl  = tid & 3;
    const int cp   = (scl - (srow >> 1)) & 3;
    const size_t ga0 = (size_t)(row0 + srow) * K + cp * 8;
    const size_t ga1 = (size_t)(row0 + 64 + srow) * K + cp * 8;
    const size_t gb0 = (size_t)(col0 + srow) * K + cp * 8;
    const size_t gb1 = (size_t)(col0 + 64 + srow) * K + cp * 8;
    const int l0 = tid * 8, l1 = 2048 + tid * 8;

    floatx4 acc[4][4];
#pragma unroll
    for (int i = 0; i < 4; i++)
#pragma unroll
        for (int j = 0; j < 4; j++) acc[i][j] = (floatx4){0.f, 0.f, 0.f, 0.f};

    for (int k0 = 0; k0 < K; k0 += 32) {
        __syncthreads();
        gload16(A + ga0 + k0,   Ah + l0);
        gload16(A + ga1 + k0,   Ah + l1);
        gload16(BTh + gb0 + k0, Bh + l0);
        gload16(BTh + gb1 + k0, Bh + l1);
        __syncthreads();

        short8 ah[4], bh[4];
#pragma unroll
        for (int t = 0; t < 4; t++) {
            ah[t] = *(const short8*)(Ah + lds_off(wm + t * 16 + lane15, quad));
            bh[t] = *(const short8*)(Bh + lds_off(wn + t * 16 + lane15, quad));
        }
#pragma unroll
        for (int i = 0; i < 4; i++)
#pragma unroll
            for (int j = 0; j < 4; j++)
                acc[i][j] = __builtin_amdgcn_mfma_f32_16x16x32_bf16(ah[i], bh[j], acc[i][j], 0, 0, 0);
    }

#pragma unroll
    for (int i = 0; i < 4; i++)
#pragma unroll
        for (int j = 0; j < 4; j++) {
            const int gc = col0 + wn + j * 16 + lane15;
            const int rb = row0 + wm + i * 16 + quad * 4;
            const float bv = bias ? bias[gc] : 0.f;
#pragma unroll
            for (int rr = 0; rr < 4; rr++) {
                const size_t o = (size_t)(rb + rr) * N + gc;
                float v = acc[i][j][rr] + bv;
                if (relu) v = fmaxf(v, 0.f);
                Cbf[o] = f2bf(v);
            }
        }
}

// ---------------------------------------------------------------------------
// Plain bf16 GEMM: A [M][K], B hi plane [N][K]: C = A @ B^T (+bias, relu)
// 128M x 64N tile, BK=64. Output bf16 (Cbf) and/or f32 (Cf). Slab-swizzled.
// Used for values T2 (N=512: 128^2 grid would be only 384 blocks = 1.5/CU,
// below the residency knee -- n64's 768 blocks wins; r1/r7 lesson).
// ---------------------------------------------------------------------------
__global__ __launch_bounds__(256) void gemm_bf16_n64(
    const ushort* __restrict__ A, const ushort* __restrict__ BTh,
    const float* __restrict__ bias,
    ushort* __restrict__ Cbf, float* __restrict__ Cf,
    int M, int N, int K, int relu)
{
    __shared__ ushort Ah[128 * 64];
    __shared__ ushort Bh[64 * 64];
    const int tid = threadIdx.x;
    const int lane = tid & 63, wid = tid >> 6;
    const int wm = wid * 32;
    const int lane15 = lane & 15, quad = lane >> 4;
    int bx, by; xcd_slab(bx, by);
    const int row0 = by * 128, col0 = bx * 64;

    const int srow = tid >> 2;
    const int scl  = tid & 3;
    const int cp   = (scl - (srow >> 1)) & 3;
    const size_t ga0 = (size_t)(row0 + srow) * K + cp * 8;
    const size_t ga1 = (size_t)(row0 + 64 + srow) * K + cp * 8;
    const size_t gb  = (size_t)(col0 + srow) * K + cp * 8;
    const int l0 = tid * 8, l1 = 2048 + tid * 8;

    floatx4 acc[2][4];
#pragma unroll
    for (int i = 0; i < 2; i++)
#pragma unroll
        for (int j = 0; j < 4; j++) acc[i][j] = (floatx4){0.f, 0.f, 0.f, 0.f};

    for (int k0 = 0; k0 < K; k0 += 64) {
        __syncthreads();
        gload16(A + ga0 + k0,      Ah + l0);
        gload16(A + ga1 + k0,      Ah + l1);
        gload16(A + ga0 + k0 + 32, Ah + 4096 + l0);
        gload16(A + ga1 + k0 + 32, Ah + 4096 + l1);
        gload16(BTh + gb + k0,      Bh + l0);
        gload16(BTh + gb + k0 + 32, Bh + 2048 + l0);
        __syncthreads();

#pragma unroll
        for (int kk = 0; kk < 2; kk++) {
            const int ao = kk * 4096, bo = kk * 2048;
            short8 ah[2], bh[4];
#pragma unroll
            for (int t = 0; t < 2; t++)
                ah[t] = *(const short8*)(Ah + ao + lds_off(wm + t * 16 + lane15, quad));
#pragma unroll
            for (int j = 0; j < 4; j++)
                bh[j] = *(const short8*)(Bh + bo + lds_off(j * 16 + lane15, quad));
#pragma unroll
            for (int i = 0; i < 2; i++)
#pragma unroll
                for (int j = 0; j < 4; j++)
                    acc[i][j] = __builtin_amdgcn_mfma_f32_16x16x32_bf16(ah[i], bh[j], acc[i][j], 0, 0, 0);
        }
    }

#pragma unroll
    for (int i = 0; i < 2; i++)
#pragma unroll
        for (int j = 0; j < 4; j++) {
            const int gc = col0 + j * 16 + lane15;
            const int rb = row0 + wm + i * 16 + quad * 4;
            const float bv = bias ? bias[gc] : 0.f;
#pragma unroll
            for (int rr = 0; rr < 4; rr++) {
                const size_t o = (size_t)(rb + rr) * N + gc;
                float v = acc[i][j][rr] + bv;
                if (relu) v = fmaxf(v, 0.f);
                if (Cbf) Cbf[o] = f2bf(v);
                if (Cf)  Cf[o] = v;
            }
        }
}

// ---------------------------------------------------------------------------
// Prep kernels
// ---------------------------------------------------------------------------
__global__ __launch_bounds__(256) void split_wt_kernel(
    const float* __restrict__ W, ushort* __restrict__ WTh,
    ushort* __restrict__ WTl, int K, int N)
{
    const int o = blockIdx.x * 256 + threadIdx.x;
    if (o < K * N) {
        const int n = o / K, k = o - n * K;
        const float x = W[(size_t)k * N + n];
        const ushort h = f2bf(x);
        WTh[o] = h;
        WTl[o] = f2bf(x - bf2f(h));
    }
}

__global__ __launch_bounds__(256) void split_pl_kernel(
    const float* __restrict__ X, ushort* __restrict__ Xh,
    ushort* __restrict__ Xl, int n)
{
    const int i = blockIdx.x * 256 + threadIdx.x;
    if (i < n) {
        const float x = X[i];
        const ushort h = f2bf(x);
        Xh[i] = h;
        Xl[i] = f2bf(x - bf2f(h));
    }
}

// ---------------------------------------------------------------------------
// LayerNorm rows of 512, f32 in / f32 out
// ---------------------------------------------------------------------------
__global__ __launch_bounds__(256) void ln_kernel(
    const float* __restrict__ X, const float* __restrict__ g,
    const float* __restrict__ b, float* __restrict__ Y, int relu)
{
    const int lane = threadIdx.x & 63;
    const int row  = blockIdx.x * 4 + (threadIdx.x >> 6);
    const float* x = X + (size_t)row * ND;
    const int d = lane * 8;

    float4 v0 = *(const float4*)(x + d);
    float4 v1 = *(const float4*)(x + d + 4);
    float s = v0.x + v0.y + v0.z + v0.w + v1.x + v1.y + v1.z + v1.w;
    float q = v0.x*v0.x + v0.y*v0.y + v0.z*v0.z + v0.w*v0.w
            + v1.x*v1.x + v1.y*v1.y + v1.z*v1.z + v1.w*v1.w;
#pragma unroll
    for (int off = 32; off; off >>= 1) {
        s += __shfl_down(s, off);
        q += __shfl_down(q, off);
    }
    s = __shfl(s, 0); q = __shfl(q, 0);
    const float mean = s * (1.f / ND);
    const float var  = q * (1.f / ND) - mean * mean;
    const float rs   = rsqrtf(var + 1e-5f);

    float4 g0 = *(const float4*)(g + d);
    float4 g1 = *(const float4*)(g + d + 4);
    float4 b0 = *(const float4*)(b + d);
    float4 b1 = *(const float4*)(b + d + 4);
    float4 o0, o1;
    o0.x = (v0.x - mean) * rs * g0.x + b0.x;
    o0.y = (v0.y - mean) * rs * g0.y + b0.y;
    o0.z = (v0.z - mean) * rs * g0.z + b0.z;
    o0.w = (v0.w - mean) * rs * g0.w + b0.w;
    o1.x = (v1.x - mean) * rs * g1.x + b1.x;
    o1.y = (v1.y - mean) * rs * g1.y + b1.y;
    o1.z = (v1.z - mean) * rs * g1.z + b1.z;
    o1.w = (v1.w - mean) * rs * g1.w + b1.w;
    if (relu) {
        o0.x = fmaxf(o0.x, 0.f); o0.y = fmaxf(o0.y, 0.f);
        o0.z = fmaxf(o0.z, 0.f); o0.w = fmaxf(o0.w, 0.f);
        o1.x = fmaxf(o1.x, 0.f); o1.y = fmaxf(o1.y, 0.f);
        o1.z = fmaxf(o1.z, 0.f); o1.w = fmaxf(o1.w, 0.f);
    }
    float* y = Y + (size_t)row * ND;
    *(float4*)(y + d)     = o0;
    *(float4*)(y + d + 4) = o1;
}

// LayerNorm rows of 512, planes in / planes out
__global__ __launch_bounds__(256) void ln_pl_kernel(
    const ushort* __restrict__ Xh, const ushort* __restrict__ Xl,
    const float* __restrict__ g, const float* __restrict__ b,
    ushort* __restrict__ Yh, ushort* __restrict__ Yl)
{
    const int lane = threadIdx.x & 63;
    const int row  = blockIdx.x * 4 + (threadIdx.x >> 6);
    const int d = lane * 8;
    const size_t base = (size_t)row * ND + d;

    short8 xh = *(const short8*)(Xh + base);
    short8 xl = *(const short8*)(Xl + base);
    float v[8];
#pragma unroll
    for (int i = 0; i < 8; i++) v[i] = bf2f((ushort)xh[i]) + bf2f((ushort)xl[i]);

    float s = 0.f, q = 0.f;
#pragma unroll
    for (int i = 0; i < 8; i++) { s += v[i]; q += v[i] * v[i]; }
#pragma unroll
    for (int off = 32; off; off >>= 1) {
        s += __shfl_down(s, off);
        q += __shfl_down(q, off);
    }
    s = __shfl(s, 0); q = __shfl(q, 0);
    const float mean = s * (1.f / ND);
    const float var  = q * (1.f / ND) - mean * mean;
    const float rs   = rsqrtf(var + 1e-5f);

    short8 yh, yl;
#pragma unroll
    for (int i = 0; i < 8; i++) {
        const float o = (v[i] - mean) * rs * g[d + i] + b[d + i];
        const ushort h = f2bf(o);
        yh[i] = (short)h;
        yl[i] = (short)f2bf(o - bf2f(h));
    }
    *(short8*)(Yh + base) = yh;
    *(short8*)(Yl + base) = yl;
}

__global__ __launch_bounds__(256) void sqnorm_pl_kernel(
    const ushort* __restrict__ Xh, const ushort* __restrict__ Xl,
    float* __restrict__ sq)
{
    const int lane = threadIdx.x & 63;
    const int row  = blockIdx.x * 4 + (threadIdx.x >> 6);
    const size_t base = (size_t)row * ND + lane * 8;
    short8 xh = *(const short8*)(Xh + base);
    short8 xl = *(const short8*)(Xl + base);
    float q = 0.f;
#pragma unroll
    for (int i = 0; i < 8; i++) {
        float v = bf2f((ushort)xh[i]) + bf2f((ushort)xl[i]);
        q += v * v;
    }
#pragma unroll
    for (int off = 32; off; off >>= 1) q += __shfl_down(q, off);
    if (lane == 0) sq[row] = q;
}

// ---------------------------------------------------------------------------
// Two-stage exact top-96: adaptive-range radix select.
// ---------------------------------------------------------------------------
__device__ __forceinline__ unsigned fkey(float f)
{
    unsigned u = __float_as_uint(f);
    return (u & 0x80000000u) ? ~u : (u | 0x80000000u);
}
__device__ __forceinline__ float inv_fkey(unsigned u)
{
    return __uint_as_float((u & 0x80000000u) ? (u & 0x7FFFFFFFu) : ~u);
}

struct SelState {
    unsigned lo;
    unsigned long long hi;   // exclusive
    int krem;
    int done;
    unsigned long long T;    // threshold
    int need;                // how many keys == T to take
};

template <int KPT>
__device__ __forceinline__ void adaptive_select(
    const unsigned (&key)[KPT], unsigned* hist, unsigned* wtot,
    SelState* st, int tid, int kwant)
{
    const int lane = tid & 63, wid = tid >> 6;

    unsigned mn = 0xFFFFFFFFu, mx = 0u;
#pragma unroll
    for (int j = 0; j < KPT; j++) {
        mn = min(mn, key[j]);
        mx = max(mx, key[j]);
    }
#pragma unroll
    for (int off = 32; off; off >>= 1) {
        mn = min(mn, (unsigned)__shfl_down((int)mn, off));
        mx = max(mx, (unsigned)__shfl_down((int)mx, off));
    }
    if (lane == 0) { hist[wid] = mn; hist[8 + wid] = mx; }
    if (tid == 0) st->done = 0;
    __syncthreads();
    if (tid == 0) {
        unsigned gmn = min(min(hist[0], hist[1]), min(hist[2], hist[3]));
        unsigned gmx = max(max(hist[8], hist[9]), max(hist[10], hist[11]));
        st->lo = gmn;
        st->hi = (unsigned long long)gmx + 1ull;
        st->krem = kwant;
    }
    __syncthreads();

    for (int iter = 0; iter < 6 && !st->done; iter++) {
        const unsigned lo = st->lo;
        const unsigned long long hi = st->hi;
        const int krem = st->krem;
        const unsigned long long span = hi - lo;
        int shift = 0;
        if (span > 256ull) {
            const int nb = 64 - __builtin_clzll(span - 1ull);
            shift = nb - 8;
        }
        hist[tid] = 0u;
        __syncthreads();
#pragma unroll
        for (int j = 0; j < KPT; j++) {
            const unsigned u = key[j];
            if (u >= lo && (unsigned long long)u < hi)
                atomicAdd(&hist[(u - lo) >> shift], 1u);
        }
        __syncthreads();
        const unsigned c = hist[tid];
        unsigned v = c;
#pragma unroll
        for (int off = 1; off < 64; off <<= 1) {
            const unsigned t = (unsigned)__shfl_up((int)v, off);
            if (lane >= off) v += t;
        }
        if (lane == 63) wtot[wid] = v;
        __syncthreads();
        unsigned pre = 0;
        for (int w = 0; w < 3; w++) pre += (w < wid) ? wtot[w] : 0u;
        const int incl = (int)(v + pre);
        const int excl = incl - (int)c;
        if (excl < krem && incl >= krem) {
            const unsigned long long binlo =
                (unsigned long long)lo + ((unsigned long long)tid << shift);
            if (shift == 0) {
                st->T = binlo;
                st->need = krem - excl;
                st->done = 1;
            } else if (incl == krem) {
                st->T = binlo + (1ull << shift);
                st->need = 0;
                st->done = 1;
            } else {
                st->lo = (unsigned)binlo;
                const unsigned long long nhi = binlo + (1ull << shift);
                st->hi = nhi < hi ? nhi : hi;
                st->krem = krem - excl;
            }
        }
        __syncthreads();
    }
}

// Phase 1: per-(row, 4096-segment) top-96. float4 loads (16B/lane).
// Element index of key[j]: tid*4 + (j>>2)*1024 + (j&3). Selection is
// order-independent (radix count).
__global__ __launch_bounds__(256) void topk_seg(
    const float* __restrict__ S, unsigned* __restrict__ K1key,
    int* __restrict__ K1idx)
{
    const int r = blockIdx.y, seg = blockIdx.x;
    const float* p = S + (size_t)r * NN + seg * TK_SEG;
    __shared__ unsigned hist[256];
    __shared__ unsigned wtot[4];
    __shared__ SelState st;
    __shared__ int cA, cB;
    const int tid = threadIdx.x;

    unsigned key[16];
#pragma unroll
    for (int j = 0; j < 4; j++) {
        float4 v = *(const float4*)(p + tid * 4 + j * 1024);
        key[j * 4 + 0] = fkey(v.x);
        key[j * 4 + 1] = fkey(v.y);
        key[j * 4 + 2] = fkey(v.z);
        key[j * 4 + 3] = fkey(v.w);
    }

    if (tid == 0) { cA = 0; cB = 0; }
    adaptive_select<16>(key, hist, wtot, &st, tid, NC);

    const unsigned long long T = st.T;
    const int need = st.need;
    const int cntLess = NC - need;
    const size_t obase = ((size_t)r * TK_SPLIT + seg) * NC;
#pragma unroll
    for (int j = 0; j < 16; j++) {
        const unsigned u = key[j];
        const int eidx = seg * TK_SEG + tid * 4 + (j >> 2) * 1024 + (j & 3);
        if ((unsigned long long)u < T) {
            const int pos = atomicAdd(&cA, 1);
            K1key[obase + pos] = u;
            K1idx[obase + pos] = eidx;
        } else if ((unsigned long long)u == T) {
            const int pos = atomicAdd(&cB, 1);
            if (pos < need) {
                K1key[obase + cntLess + pos] = u;
                K1idx[obase + cntLess + pos] = eidx;
            }
        }
    }
}

__global__ __launch_bounds__(256) void topk_merge(
    const unsigned* __restrict__ K1key, const int* __restrict__ K1idx,
    int* __restrict__ idx_out, float* __restrict__ val_out, int b0)
{
    const int r = blockIdx.x;
    const int b = b0 + r;
    __shared__ unsigned hist[256];
    __shared__ unsigned wtot[4];
    __shared__ SelState st;
    __shared__ int cA, cB;
    const int tid = threadIdx.x;
    const size_t ibase = (size_t)r * TK_CAND;

    unsigned key[6];
    int      kidx[6];
#pragma unroll
    for (int j = 0; j < 6; j++) {
        key[j]  = K1key[ibase + tid + j * 256];
        kidx[j] = K1idx[ibase + tid + j * 256];
    }

    if (tid == 0) { cA = 0; cB = 0; }
    adaptive_select<6>(key, hist, wtot, &st, tid, NC);

    const unsigned long long T = st.T;
    const int need = st.need;
    const int cntLess = NC - need;
#pragma unroll
    for (int j = 0; j < 6; j++) {
        const unsigned u = key[j];
        if ((unsigned long long)u < T) {
            const int pos = atomicAdd(&cA, 1);
            idx_out[b * NC + pos] = kidx[j];
            val_out[b * NC + pos] = inv_fkey(u);
        } else if ((unsigned long long)u == T) {
            const int pos = atomicAdd(&cB, 1);
            if (pos < need) {
                idx_out[b * NC + cntLess + pos] = kidx[j];
                val_out[b * NC + cntLess + pos] = inv_fkey(u);
            }
        }
    }
}

// ---------------------------------------------------------------------------
__global__ __launch_bounds__(128) void probs_kernel(
    const float* __restrict__ svals, float* __restrict__ probs)
{
    const int b = blockIdx.x;
    const int tid = threadIdx.x;
    __shared__ float red[128];
    const bool valid = tid < NC;
    float s = valid ? -svals[b * NC + tid] : -3.4e38f;
    red[tid] = s;
    __syncthreads();
#pragma unroll
    for (int off = 64; off; off >>= 1) {
        if (tid < off) red[tid] = fmaxf(red[tid], red[tid + off]);
        __syncthreads();
    }
    const float m = red[0];
    __syncthreads();
    float e = valid ? expf(s - m) : 0.f;
    red[tid] = e;
    __syncthreads();
#pragma unroll
    for (int off = 64; off; off >>= 1) {
        if (tid < off) red[tid] += red[tid + off];
        __syncthreads();
    }
    const float sum = red[0];
    if (valid) probs[b * NC + tid] = e / sum;
}

// ctx: xin given as planes (encoder-out x). Grid (BBD, 2): blockIdx.y picks
// a 256-wide d-half.
__global__ __launch_bounds__(256) void ctx_kernel(
    const float* __restrict__ VAL, const float* __restrict__ probs,
    const float* __restrict__ cand_y, const int* __restrict__ idx,
    const float* __restrict__ labW, const float* __restrict__ labb,
    const ushort* __restrict__ xinh, const ushort* __restrict__ xinl,
    float* __restrict__ xout, int b0)
{
    const int b_loc = blockIdx.x;
    const int b = b0 + b_loc;
    const int tid = threadIdx.x;
    __shared__ float pv[NC];
    __shared__ float red[256];
    float py_part = 0.f;
    if (tid < NC) {
        float p = probs[b * NC + tid];
        pv[tid] = p;
        py_part = p * cand_y[idx[b * NC + tid]];
    }
    red[tid] = py_part;
    __syncthreads();
#pragma unroll
    for (int off = 128; off; off >>= 1) {
        if (tid < off) red[tid] += red[tid + off];
        __syncthreads();
    }
    const float py = red[0];

    const int d = blockIdx.y * 256 + tid;   // one d per thread, 2 halves
    const float* vp = VAL + (size_t)b_loc * NC * ND + d;
    float acc = 0.f;
#pragma unroll 8
    for (int c = 0; c < NC; c++) acc += pv[c] * vp[(size_t)c * ND];
    float ctx = acc + py * labW[d] + labb[d];
    const size_t o = (size_t)b * ND + d;
    xout[o] = bf2f(xinh[o]) + bf2f(xinl[o]) + ctx;
}

__global__ __launch_bounds__(64) void head_kernel(
    const float* __restrict__ X, const float* __restrict__ hW,
    const float* __restrict__ hb, float* __restrict__ out)
{
    const int b = blockIdx.x;
    const int lane = threadIdx.x;
    const float* x = X + (size_t)b * ND;
    float acc = 0.f;
#pragma unroll
    for (int j = 0; j < 8; j++) {
        int d = lane + 64 * j;
        acc += x[d] * hW[d];
    }
#pragma unroll
    for (int off = 32; off; off >>= 1) acc += __shfl_down(acc, off);
    if (lane == 0) out[b] = acc + hb[0];
}

// ---------------------------------------------------------------------------
extern "C" void kernel_launch(void* const* d_in, const int* in_sizes, int n_in,
                              void* d_out, int out_size, void* d_ws, size_t ws_size,
                              hipStream_t stream)
{
    const float* x_num    = (const float*)d_in[0];
    const float* cand_num = (const float*)d_in[1];
    const float* cand_y   = (const float*)d_in[2];
    const float* lin_W    = (const float*)d_in[3];
    const float* lin_b    = (const float*)d_in[4];
    const float* e_W1     = (const float*)d_in[5];
    const float* e_b1     = (const float*)d_in[6];
    const float* e_W2     = (const float*)d_in[7];
    const float* e_b2     = (const float*)d_in[8];
    const float* mix_g    = (const float*)d_in[9];
    const float* mix_b    = (const float*)d_in[10];
    const float* K_W      = (const float*)d_in[11];
    const float* K_b      = (const float*)d_in[12];
    const float* lab_W    = (const float*)d_in[13];
    const float* lab_b    = (const float*)d_in[14];
    const float* T_W1     = (const float*)d_in[15];
    const float* T_b1     = (const float*)d_in[16];
    const float* T_W2     = (const float*)d_in[17];
    const float* p_ln_g   = (const float*)d_in[18];
    const float* p_ln_b   = (const float*)d_in[19];
    const float* p_W1     = (const float*)d_in[20];
    const float* p_b1     = (const float*)d_in[21];
    const float* p_W2     = (const float*)d_in[22];
    const float* p_b2     = (const float*)d_in[23];
    const float* h_ln_g   = (const float*)d_in[24];
    const float* h_ln_b   = (const float*)d_in[25];
    const float* h_W      = (const float*)d_in[26];
    const float* h_b      = (const float*)d_in[27];
    float* out = (float*)d_out;
    (void)in_sizes; (void)n_in; (void)out_size;

    const int NTOT = NN + NB;   // 66560 = 5*13312 = 8*8320

    // ---- workspace layout ----
    size_t off = 0;
    auto ralloc = [&](size_t bytes) -> void* {
        void* p = (char*)d_ws + off;
        off += (bytes + 255) & ~(size_t)255;
        return p;
    };
    auto falloc = [&](size_t n) -> float*  { return (float*)ralloc(n * 4); };
    auto ualloc = [&](size_t n) -> ushort* { return (ushort*)ralloc(n * 2); };

    // bf16 plane weights [N][K]
    ushort* WP_lin_h = ualloc((size_t)ND * NF);
    ushort* WP_lin_l = ualloc((size_t)ND * NF);
    ushort* WP_e1_h  = ualloc((size_t)NDB * ND);
    ushort* WP_e1_l  = ualloc((size_t)NDB * ND);
    ushort* WP_e2_h  = ualloc((size_t)ND * NDB);
    ushort* WP_e2_l  = ualloc((size_t)ND * NDB);
    ushort* WP_kw_h  = ualloc((size_t)ND * ND);
    ushort* WP_kw_l  = ualloc((size_t)ND * ND);
    ushort* WP_t1_h  = ualloc((size_t)NDB * ND);
    ushort* WP_t1_l  = ualloc((size_t)NDB * ND);
    ushort* WP_t2_h  = ualloc((size_t)ND * NDB);
    ushort* WP_t2_l  = ualloc((size_t)ND * NDB);
    ushort* WP_p1_h  = ualloc((size_t)NDB * ND);
    ushort* WP_p1_l  = ualloc((size_t)NDB * ND);
    ushort* WP_p2_h  = ualloc((size_t)ND * NDB);
    ushort* WP_p2_l  = ualloc((size_t)ND * NDB);

    // keys for candidates + x (x rows are the tail 1024)
    ushort* R_CKh = ualloc((size_t)NTOT * ND);
    ushort* R_CKl = ualloc((size_t)NTOT * ND);
    float*  R_sq  = falloc(NTOT);

    // persistent x activations
    ushort* X2h = ualloc((size_t)NB * ND);
    ushort* X2l = ualloc((size_t)NB * ND);
    ushort* Lxh = ualloc((size_t)NB * ND);
    ushort* Lxl = ualloc((size_t)NB * ND);
    ushort* Tph = ualloc((size_t)NB * NDB);
    ushort* Tpl = ualloc((size_t)NB * NDB);

    int*    R_idx = (int*)ralloc((size_t)NB * NC * 4);
    float*  R_ssel= falloc((size_t)NB * NC);
    float*  R_prob= falloc((size_t)NB * NC);
    float*  R_xupd= falloc((size_t)NB * ND);
    float*  R_lnx = falloc((size_t)NB * ND);
    float*  R_x2  = falloc((size_t)NB * ND);
    float*  R_lnx2= falloc((size_t)NB * ND);
    unsigned* K1key = (unsigned*)ralloc((size_t)BB_C * TK_CAND * 4);
    int*      K1idx = (int*)ralloc((size_t)BB_C * TK_CAND * 4);

    // ---- adaptive chunk: per-row scratch = H 2048B (in-place H2) +
    //      T 4096B (CN and G overlay the T region) = 6144 B.
    //      CH=13312 (5 chunks) if workspace allows, else 8320 (8 chunks).
    int CH;
    {
        const size_t remain = (ws_size > off) ? (ws_size - off) : 0;
        CH = (remain >= (size_t)13312 * 6144 + (size_t)(4u << 20)) ? 13312 : 8320;
    }
    size_t scr_bytes = (size_t)CH * 6144;
    const size_t scores_bytes = (size_t)BB_C * NN * 4;                  // 67.1 MB
    // values: DD [M][512]bf16 + TT [M][1024]bf16 + VAL [M][512]f32
    const size_t values_bytes = (size_t)BB_D * NC * (ND*2 + NDB*2 + ND*4); // 62.9 MB
    if (scr_bytes < scores_bytes) scr_bytes = scores_bytes;
    if (scr_bytes < values_bytes) scr_bytes = values_bytes;
    char* SCR = (char*)ralloc(scr_bytes);

    // ---- 0. weight prep (split-transpose to planes) ----
    auto sw = [&](const float* W, ushort* WTh, ushort* WTl, int K, int N) {
        split_wt_kernel<<<dim3((K * N + 255) / 256), dim3(256), 0, stream>>>(W, WTh, WTl, K, N);
    };
    sw(lin_W, WP_lin_h, WP_lin_l, NF, ND);
    sw(e_W1,  WP_e1_h,  WP_e1_l,  ND, NDB);
    sw(e_W2,  WP_e2_h,  WP_e2_l,  NDB, ND);
    sw(K_W,   WP_kw_h,  WP_kw_l,  ND, ND);
    sw(T_W1,  WP_t1_h,  WP_t1_l,  ND, NDB);
    sw(T_W2,  WP_t2_h,  WP_t2_l,  NDB, ND);
    sw(p_W1,  WP_p1_h,  WP_p1_l,  ND, NDB);
    sw(p_W2,  WP_p2_h,  WP_p2_l,  NDB, ND);

    auto gn64 = [&](const ushort* Ah, const ushort* Al, const ushort* Bh,
                    const ushort* Bl, const float* bias, const ushort* resh,
                    const ushort* resl, ushort* Ch, ushort* Cl,
                    int M, int Nn, int K, int relu) {
        gemm_ss_n64<<<dim3(Nn / 64, M / 128), dim3(256), 0, stream>>>(
            Ah, Al, Bh, Bl, bias, resh, resl, Ch, Cl, M, Nn, K, relu);
    };
    auto gsm = [&](const ushort* Ah, const ushort* Al, const ushort* Bh,
                   const ushort* Bl, const float* bias, const ushort* resh,
                   const ushort* resl, const float* resf, ushort* Ch,
                   ushort* Cl, float* outf, int M, int Nn, int K, int relu) {
        gemm_ss_small<<<dim3(Nn / 64, M / 64), dim3(256), 0, stream>>>(
            Ah, Al, Bh, Bl, bias, resh, resl, resf, Ch, Cl, outf, M, Nn, K, relu);
    };

    // ---- 1. unified encode: [candidates; x] in CH-row chunks ----
    // lin/e2/kw on 64^2 gsm (residency), e1 on 128x64 n64 (r6 best config).
    {
        ushort* Hh = (ushort*)SCR;                     // [CH,512]
        ushort* Hl = Hh + (size_t)CH * ND;
        ushort* Th = Hl + (size_t)CH * ND;             // [CH,1024]
        ushort* Tl = Th + (size_t)CH * NDB;
        ushort* CNh = Th;   // overlay: CN dead once e1 writes T
        ushort* CNl = Tl;
        ushort* Gh  = Th;   // overlay: T dead after e2
        ushort* Gl  = Tl;

        for (int n0 = 0; n0 < NTOT; n0 += CH) {
            int candRows = NN - n0;
            if (candRows > CH) candRows = CH;
            if (candRows < 0)  candRows = 0;
            const int xRows = CH - candRows;   // 0 except last chunk (=NB)

            if (candRows)
                split_pl_kernel<<<dim3((candRows * NF + 255) / 256), dim3(256), 0, stream>>>(
                    cand_num + (size_t)n0 * NF, CNh, CNl, candRows * NF);
            if (xRows)
                split_pl_kernel<<<dim3((xRows * NF + 255) / 256), dim3(256), 0, stream>>>(
                    x_num, CNh + (size_t)candRows * NF, CNl + (size_t)candRows * NF,
                    xRows * NF);

            // lin: 64^2 tile, grid 8 x CH/64 (>=1040 blocks)
            gsm(CNh, CNl, WP_lin_h, WP_lin_l, lin_b, nullptr, nullptr, nullptr,
                Hh, Hl, nullptr, CH, ND, NF, 0);
            // e1: 128x64 tile, grid 16 x CH/128 (1664 @ CH=13312)
            gn64(Hh, Hl, WP_e1_h, WP_e1_l, e_b1, nullptr, nullptr,
                 Th, Tl, CH, NDB, ND, 1);
            // e2 IN-PLACE: residual = H, output overwrites H
            gsm(Th, Tl, WP_e2_h, WP_e2_l, e_b2, Hh, Hl, nullptr,
                Hh, Hl, nullptr, CH, ND, NDB, 0);

            if (xRows) {   // persist encoder-out planes for the x rows
                hipMemcpyAsync(X2h, Hh + (size_t)candRows * ND,
                               (size_t)NB * ND * 2, hipMemcpyDeviceToDevice, stream);
                hipMemcpyAsync(X2l, Hl + (size_t)candRows * ND,
                               (size_t)NB * ND * 2, hipMemcpyDeviceToDevice, stream);
            }

            ln_pl_kernel<<<dim3(CH / 4), dim3(256), 0, stream>>>(
                Hh, Hl, mix_g, mix_b, Gh, Gl);
            gsm(Gh, Gl, WP_kw_h, WP_kw_l, K_b, nullptr, nullptr, nullptr,
                R_CKh + (size_t)n0 * ND, R_CKl + (size_t)n0 * ND, nullptr,
                CH, ND, ND, 0);
            sqnorm_pl_kernel<<<dim3(CH / 4), dim3(256), 0, stream>>>(
                R_CKh + (size_t)n0 * ND, R_CKl + (size_t)n0 * ND, R_sq + n0);
        }
    }

    // x keys = tail rows of R_CK
    const ushort* kxh = R_CKh + (size_t)NN * ND;
    const ushort* kxl = R_CKl + (size_t)NN * ND;

    // ---- 2. scores (3-MFMA) + two-stage top-96 + softmax ----
    for (int b0 = 0; b0 < NB; b0 += BB_C) {
        float* S = (float*)SCR;
        gemm_ss<<<dim3(NN / 128, BB_C / 128), dim3(256), 0, stream>>>(
            kxh + (size_t)b0 * ND, kxl + (size_t)b0 * ND, R_CKh, R_CKl,
            R_sq, S, BB_C, NN, ND);
        topk_seg<<<dim3(TK_SPLIT, BB_C), dim3(256), 0, stream>>>(S, K1key, K1idx);
        topk_merge<<<dim3(BB_C), dim3(256), 0, stream>>>(K1key, K1idx,
                                                         R_idx, R_ssel, b0);
    }
    probs_kernel<<<dim3(NB), dim3(128), 0, stream>>>(R_ssel, R_prob);

    // ---- 3. values path: precomputed diff + two plain bf16 GEMMs ----
    for (int b0 = 0; b0 < NB; b0 += BB_D) {
        const int M = BB_D * NC;   // 12288
        ushort* DD  = (ushort*)SCR;                          // [M][512] bf16
        ushort* TT  = DD + (size_t)M * ND;                   // [M][1024] bf16
        float*  VAL = (float*)(TT + (size_t)M * NDB);        // [M][512] f32

        diff_pl_kernel<<<dim3((M * (ND / 8) + 255) / 256), dim3(256), 0, stream>>>(
            kxh + (size_t)b0 * ND, kxl + (size_t)b0 * ND,
            R_CKh, R_CKl, R_idx + b0 * NC, DD, M);
        // T1: DD @ t1^T (+bias, relu) -> TT bf16. 128^2 tile (m97 structure),
        // grid 8x96 = 768 blocks = 3/CU.
        gemm_bf16_128<<<dim3(NDB / 128, M / 128), dim3(256), 0, stream>>>(
            DD, WP_t1_h, T_b1, TT, M, NDB, ND, 1);
        // T2: TT @ t2^T -> VAL f32. n64 tile, grid 8x96 = 768 blocks.
        gemm_bf16_n64<<<dim3(ND / 64, M / 128), dim3(256), 0, stream>>>(
            TT, WP_t2_h, nullptr, nullptr, VAL, M, ND, NDB, 0);
        ctx_kernel<<<dim3(BB_D, 2), dim3(256), 0, stream>>>(
            VAL, R_prob, cand_y, R_idx, lab_W, lab_b, X2h, X2l, R_xupd, b0);
    }

    // ---- 4. predictor block + head (full 3-MFMA) ----
    ln_kernel<<<dim3(NB / 4), dim3(256), 0, stream>>>(R_xupd, p_ln_g, p_ln_b, R_lnx, 0);
    split_pl_kernel<<<dim3((NB * ND + 255) / 256), dim3(256), 0, stream>>>(
        R_lnx, Lxh, Lxl, NB * ND);
    gsm(Lxh, Lxl, WP_p1_h, WP_p1_l, p_b1, nullptr, nullptr, nullptr,
        Tph, Tpl, nullptr, NB, NDB, ND, 1);
    gsm(Tph, Tpl, WP_p2_h, WP_p2_l, p_b2, nullptr, nullptr, R_xupd,
        nullptr, nullptr, R_x2, NB, ND, NDB, 0);
    ln_kernel<<<dim3(NB / 4), dim3(256), 0, stream>>>(R_x2, h_ln_g, h_ln_b, R_lnx2, 1);
    head_kernel<<<dim3(NB), dim3(64), 0, stream>>>(R_lnx2, h_W, h_b, out);
}